// Round 1
// baseline (4533.619 us; speedup 1.0000x reference)
//
#include <hip/hip_runtime.h>
#include <math.h>

// ---------------- problem constants ----------------
constexpr int kB = 4, kT = 6, kN = 512, kC = 8;
constexpr int kH = 64, kF = 16, kE = 32;
constexpr int kKS = 3, kKC = 2, kHOR = 3;
constexpr int kBT = kB * kT;          // 24
constexpr int kRK = kBT * kH;         // 1536 (contraction for M)
constexpr int L_ENC = 1 + kH + kF;    // 81
constexpr int L_DEC = kH + kH + kF;   // 144
constexpr float kALPHA = 3.0f;

__device__ __forceinline__ float sigm(float x) { return 1.0f / (1.0f + __expf(-x)); }

__device__ __forceinline__ void fma44(const float4& a, const float4& b, float acc[4][4]) {
    acc[0][0] += a.x*b.x; acc[0][1] += a.x*b.y; acc[0][2] += a.x*b.z; acc[0][3] += a.x*b.w;
    acc[1][0] += a.y*b.x; acc[1][1] += a.y*b.y; acc[1][2] += a.y*b.z; acc[1][3] += a.y*b.w;
    acc[2][0] += a.z*b.x; acc[2][1] += a.z*b.y; acc[2][2] += a.z*b.z; acc[2][3] += a.z*b.w;
    acc[3][0] += a.w*b.x; acc[3][1] += a.w*b.y; acc[3][2] += a.w*b.z; acc[3][3] += a.w*b.w;
}

// ---------------- phase 1: adaptive graph ----------------

// Upr[n][bt*64+h] = tanh(3 * sum_c X[bt,n,c] * Wu[c,h]); Vpr likewise.
__global__ __launch_bounds__(256) void k_uvproj_s(
    const float* __restrict__ X, const float* __restrict__ Wu, const float* __restrict__ Wv,
    float* __restrict__ Upr, float* __restrict__ Vpr)
{
    int idx = blockIdx.x * blockDim.x + threadIdx.x;
    if (idx >= kN * kBT * kH) return;
    int h = idx % kH; int bt = (idx / kH) % kBT; int n = idx / (kH * kBT);
    const float* xr = X + ((size_t)bt * kN + n) * kC;
    float u = 0.f, v = 0.f;
#pragma unroll
    for (int c = 0; c < kC; ++c) { float x = xr[c]; u += x * Wu[c*kH + h]; v += x * Wv[c*kH + h]; }
    Upr[(size_t)n * kRK + bt * kH + h] = tanhf(kALPHA * u);
    Vpr[(size_t)n * kRK + bt * kH + h] = tanhf(kALPHA * v);
}

// Uc[(bt*8+c)][h] = tanh(3 * sum_n X[bt,n,c] * WuC[n,h])
__global__ __launch_bounds__(256) void k_uvproj_c(
    const float* __restrict__ X, const float* __restrict__ WuC, const float* __restrict__ WvC,
    float* __restrict__ Uc, float* __restrict__ Vc)
{
    int idx = blockIdx.x * blockDim.x + threadIdx.x;
    if (idx >= kBT * kC * kH) return;
    int h = idx % kH; int c = (idx / kH) % kC; int bt = idx / (kH * kC);
    const float* xb = X + (size_t)bt * kN * kC + c;
    float u = 0.f, v = 0.f;
    for (int n = 0; n < kN; ++n) { float x = xb[n*kC]; u += x * WuC[n*kH + h]; v += x * WvC[n*kH + h]; }
    Uc[(bt*kC + c)*kH + h] = tanhf(kALPHA * u);
    Vc[(bt*kC + c)*kH + h] = tanhf(kALPHA * v);
}

// Mc[c,d] = sum_{bt,h} Uc[bt*8+c][h] * Vc[bt*8+d][h]   (one block of 64 threads)
__global__ void k_mc(const float* __restrict__ Uc, const float* __restrict__ Vc, float* __restrict__ Mc)
{
    int t = threadIdx.x; if (t >= 64) return;
    int d = t % 8, c = t / 8;
    float s = 0.f;
    for (int bt = 0; bt < kBT; ++bt)
        for (int h = 0; h < kH; ++h)
            s += Uc[(bt*8 + c)*kH + h] * Vc[(bt*8 + d)*kH + h];
    Mc[c*8 + d] = s;
}

// P[i,:] = softmax_j(relu(M[i,j] - M[j,i]))
__global__ __launch_bounds__(256) void k_softmax_pm(const float* __restrict__ M, float* __restrict__ P, int S)
{
    int i = blockIdx.x, tid = threadIdx.x;
    __shared__ float sm[256];
    float mx = -1e30f;
    for (int j = tid; j < S; j += 256) {
        float v = fmaxf(M[(size_t)i*S + j] - M[(size_t)j*S + i], 0.f);
        mx = fmaxf(mx, v);
    }
    sm[tid] = mx; __syncthreads();
    for (int s = 128; s > 0; s >>= 1) { if (tid < s) sm[tid] = fmaxf(sm[tid], sm[tid+s]); __syncthreads(); }
    mx = sm[0]; __syncthreads();
    float sum = 0.f;
    for (int j = tid; j < S; j += 256) {
        float v = fmaxf(M[(size_t)i*S + j] - M[(size_t)j*S + i], 0.f);
        float e = __expf(v - mx);
        P[(size_t)i*S + j] = e; sum += e;
    }
    sm[tid] = sum; __syncthreads();
    for (int s = 128; s > 0; s >>= 1) { if (tid < s) sm[tid] += sm[tid+s]; __syncthreads(); }
    float inv = 1.f / sm[0];
    __syncthreads();
    for (int j = tid; j < S; j += 256) P[(size_t)i*S + j] *= inv;
}

// nf[i] = [rowsum A, rowsum P]
__global__ __launch_bounds__(256) void k_nf(const float* __restrict__ A, const float* __restrict__ P,
                                            float* __restrict__ nf, int S)
{
    int i = blockIdx.x, tid = threadIdx.x;
    __shared__ float sa[256], sp[256];
    float a = 0.f, p = 0.f;
    for (int j = tid; j < S; j += 256) { a += A[(size_t)i*S + j]; p += P[(size_t)i*S + j]; }
    sa[tid] = a; sp[tid] = p; __syncthreads();
    for (int s = 128; s > 0; s >>= 1) { if (tid < s) { sa[tid] += sa[tid+s]; sp[tid] += sp[tid+s]; } __syncthreads(); }
    if (!tid) { nf[i*2] = sa[0]; nf[i*2+1] = sp[0]; }
}

// An = A @ nf ; Pn = P @ nf
__global__ __launch_bounds__(256) void k_anpn(const float* __restrict__ A, const float* __restrict__ P,
                                              const float* __restrict__ nf,
                                              float* __restrict__ An, float* __restrict__ Pn, int S)
{
    int i = blockIdx.x, tid = threadIdx.x;
    __shared__ float s0[256], s1[256], s2[256], s3[256];
    float a0 = 0, a1 = 0, p0 = 0, p1 = 0;
    for (int j = tid; j < S; j += 256) {
        float av = A[(size_t)i*S + j], pv = P[(size_t)i*S + j];
        float n0 = nf[2*j], n1 = nf[2*j + 1];
        a0 += av*n0; a1 += av*n1; p0 += pv*n0; p1 += pv*n1;
    }
    s0[tid]=a0; s1[tid]=a1; s2[tid]=p0; s3[tid]=p1; __syncthreads();
    for (int s = 128; s > 0; s >>= 1) {
        if (tid < s) { s0[tid]+=s0[tid+s]; s1[tid]+=s1[tid+s]; s2[tid]+=s2[tid+s]; s3[tid]+=s3[tid+s]; }
        __syncthreads();
    }
    if (!tid) { An[i*2]=s0[0]; An[i*2+1]=s1[0]; Pn[i*2]=s2[0]; Pn[i*2+1]=s3[0]; }
}

// hidA = relu(An @ w1[ia] + b1[ia]); hidP = relu(Pn @ w1[ip] + b1[ip])
__global__ __launch_bounds__(256) void k_mlp1(
    const float* __restrict__ An, const float* __restrict__ Pn,
    const float* __restrict__ w1, const float* __restrict__ b1, int ia, int ip,
    float* __restrict__ hidA, float* __restrict__ hidP, int M)
{
    int idx = blockIdx.x * blockDim.x + threadIdx.x;
    if (idx >= M * 256) return;
    int o = idx % 256, i = idx / 256;
    const float* w1a = w1 + (size_t)ia * 512; const float* b1a = b1 + (size_t)ia * 256;
    const float* w1p = w1 + (size_t)ip * 512; const float* b1p = b1 + (size_t)ip * 256;
    float a = An[i*2] * w1a[o] + An[i*2+1] * w1a[256 + o] + b1a[o];
    float p = Pn[i*2] * w1p[o] + Pn[i*2+1] * w1p[256 + o] + b1p[o];
    hidA[(size_t)i*256 + o] = fmaxf(a, 0.f);
    hidP[(size_t)i*256 + o] = fmaxf(p, 0.f);
}

// C = A * B^T with optional fuse epilogue (mode 1: G = sig(C)*Apr + (1-sig)*Ppr)
__global__ __launch_bounds__(256) void k_gemm_nt(
    const float* __restrict__ A, const float* __restrict__ Bm, float* __restrict__ Cm,
    int M, int Ncols, int K, int mode,
    const float* __restrict__ Apr, const float* __restrict__ Ppr)
{
    __shared__ __align__(16) float sA[16][68];
    __shared__ __align__(16) float sB[16][68];
    int tid = threadIdx.x, tx = tid & 15, ty = tid >> 4;
    int i0 = blockIdx.y * 64, j0 = blockIdx.x * 64;
    float acc[4][4] = {};
    for (int k0 = 0; k0 < K; k0 += 16) {
#pragma unroll
        for (int it = 0; it < 4; ++it) {
            int r = tid + it * 256;
            int kk = r & 15, ii = r >> 4;
            int gi = i0 + ii, gj = j0 + ii;
            sA[kk][ii] = (gi < M)     ? A[(size_t)gi*K + k0 + kk]  : 0.f;
            sB[kk][ii] = (gj < Ncols) ? Bm[(size_t)gj*K + k0 + kk] : 0.f;
        }
        __syncthreads();
#pragma unroll
        for (int kk = 0; kk < 16; ++kk) {
            float4 a = *(const float4*)&sA[kk][ty*4];
            float4 b = *(const float4*)&sB[kk][tx*4];
            fma44(a, b, acc);
        }
        __syncthreads();
    }
#pragma unroll
    for (int i = 0; i < 4; ++i) {
        int gi = i0 + ty*4 + i; if (gi >= M) continue;
#pragma unroll
        for (int j = 0; j < 4; ++j) {
            int gj = j0 + tx*4 + j; if (gj >= Ncols) continue;
            float v = acc[i][j];
            if (mode == 1) {
                float s = sigm(v);
                v = s * Apr[(size_t)gi*Ncols + gj] + (1.f - s) * Ppr[(size_t)gi*Ncols + gj];
            }
            Cm[(size_t)gi*Ncols + gj] = v;
        }
    }
}

// C = A1@B1 + A2@B2 + bias1 + bias2   (all row-major, B is [K, Ncols])
__global__ __launch_bounds__(256) void k_gemm_nn_dual(
    const float* __restrict__ A1, const float* __restrict__ B1,
    const float* __restrict__ A2, const float* __restrict__ B2,
    const float* __restrict__ bias1, const float* __restrict__ bias2,
    float* __restrict__ Cm, int M, int Ncols, int K)
{
    __shared__ __align__(16) float sA[16][68];
    __shared__ __align__(16) float sB[16][68];
    int tid = threadIdx.x, tx = tid & 15, ty = tid >> 4;
    int i0 = blockIdx.y * 64, j0 = blockIdx.x * 64;
    float acc[4][4] = {};
    for (int kq = 0; kq < 2*K; kq += 16) {
        const float* Aq; const float* Bq; int k0;
        if (kq < K) { Aq = A1; Bq = B1; k0 = kq; } else { Aq = A2; Bq = B2; k0 = kq - K; }
#pragma unroll
        for (int it = 0; it < 4; ++it) {
            int r = tid + it * 256;
            int kk = r & 15, ii = r >> 4;
            int gi = i0 + ii;
            sA[kk][ii] = (gi < M) ? Aq[(size_t)gi*K + k0 + kk] : 0.f;
        }
#pragma unroll
        for (int it = 0; it < 4; ++it) {
            int r = tid + it * 256;
            int jj = r & 63, kk = r >> 6;
            int gj = j0 + jj;
            sB[kk][jj] = (gj < Ncols) ? Bq[(size_t)(k0 + kk)*Ncols + gj] : 0.f;
        }
        __syncthreads();
#pragma unroll
        for (int kk = 0; kk < 16; ++kk) {
            float4 a = *(const float4*)&sA[kk][ty*4];
            float4 b = *(const float4*)&sB[kk][tx*4];
            fma44(a, b, acc);
        }
        __syncthreads();
    }
#pragma unroll
    for (int i = 0; i < 4; ++i) {
        int gi = i0 + ty*4 + i; if (gi >= M) continue;
#pragma unroll
        for (int j = 0; j < 4; ++j) {
            int gj = j0 + tx*4 + j; if (gj >= Ncols) continue;
            Cm[(size_t)gi*Ncols + gj] = acc[i][j] + bias1[gj] + bias2[gj];
        }
    }
}

// G2 = 2*G@G - I   (512x512)
__global__ __launch_bounds__(256) void k_cheby(const float* __restrict__ G, float* __restrict__ G2)
{
    __shared__ __align__(16) float sA[16][68];
    __shared__ __align__(16) float sB[16][68];
    int tid = threadIdx.x, tx = tid & 15, ty = tid >> 4;
    int i0 = blockIdx.y * 64, j0 = blockIdx.x * 64;
    float acc[4][4] = {};
    for (int k0 = 0; k0 < kN; k0 += 16) {
#pragma unroll
        for (int it = 0; it < 4; ++it) {
            int r = tid + it * 256;
            int kk = r & 15, ii = r >> 4;
            sA[kk][ii] = G[(size_t)(i0 + ii)*kN + k0 + kk];
        }
#pragma unroll
        for (int it = 0; it < 4; ++it) {
            int r = tid + it * 256;
            int jj = r & 63, kk = r >> 6;
            sB[kk][jj] = G[(size_t)(k0 + kk)*kN + j0 + jj];
        }
        __syncthreads();
#pragma unroll
        for (int kk = 0; kk < 16; ++kk) {
            float4 a = *(const float4*)&sA[kk][ty*4];
            float4 b = *(const float4*)&sB[kk][tx*4];
            fma44(a, b, acc);
        }
        __syncthreads();
    }
#pragma unroll
    for (int i = 0; i < 4; ++i) {
        int gi = i0 + ty*4 + i;
#pragma unroll
        for (int j = 0; j < 4; ++j) {
            int gj = j0 + tx*4 + j;
            G2[(size_t)gi*kN + gj] = 2.f * acc[i][j] - (gi == gj ? 1.f : 0.f);
        }
    }
}

// ---------------- GRU cell kernels ----------------

// Y[ki,b][m,col] = sum_n G_k[n,m] * Xin[b][n,col]   ; grid.z: ki*4+b, ki 0->Gs, 1->Gs2
__global__ __launch_bounds__(256) void k_gemm_t1(
    const float* __restrict__ Gs1, const float* __restrict__ Gs2v,
    const float* __restrict__ Xin, float* __restrict__ Yout, int CL)
{
    int ki = blockIdx.z >> 2, b = blockIdx.z & 3;
    const float* A  = ki ? Gs2v : Gs1;                      // [512(n), 512(m)]
    const float* Bm = Xin + (size_t)b * kN * CL;            // [512, CL]
    float* Cm = Yout + (size_t)(ki*kB + b) * kN * CL;
    int m0 = blockIdx.y * 64, c0 = blockIdx.x * 64;
    __shared__ __align__(16) float sA[16][68];
    __shared__ __align__(16) float sB[16][68];
    int tid = threadIdx.x, tx = tid & 15, ty = tid >> 4;
    float acc[4][4] = {};
    for (int k0 = 0; k0 < kN; k0 += 16) {
#pragma unroll
        for (int it = 0; it < 4; ++it) {
            int r = tid + it * 256;
            int mm = r & 63, kk = r >> 6;
            sA[kk][mm] = A[(size_t)(k0 + kk)*kN + m0 + mm];
        }
#pragma unroll
        for (int it = 0; it < 4; ++it) {
            int r = tid + it * 256;
            int cc = r & 63, kk = r >> 6;
            int col = c0 + cc;
            sB[kk][cc] = (col < CL) ? Bm[(size_t)(k0 + kk)*CL + col] : 0.f;
        }
        __syncthreads();
#pragma unroll
        for (int kk = 0; kk < 16; ++kk) {
            float4 a = *(const float4*)&sA[kk][ty*4];
            float4 b4 = *(const float4*)&sB[kk][tx*4];
            fma44(a, b4, acc);
        }
        __syncthreads();
    }
#pragma unroll
    for (int i = 0; i < 4; ++i) {
        int m = m0 + ty*4 + i;
#pragma unroll
        for (int j = 0; j < 4; ++j) {
            int col = c0 + tx*4 + j;
            if (col < CL) Cm[(size_t)m*CL + col] = acc[i][j];
        }
    }
}

// XH = [Xt | Ht | featx] for encoder step t
__global__ __launch_bounds__(256) void k_build_xh_enc(
    const float* __restrict__ X, int t, const float* __restrict__ Ht,
    const float* __restrict__ featr, float* __restrict__ XH)
{
    int idx = blockIdx.x * blockDim.x + threadIdx.x;
    if (idx >= kB*kN*kC*L_ENC) return;
    int l = idx % L_ENC;
    int c = (idx / L_ENC) % kC;
    int m = (idx / (L_ENC*kC)) % kN;
    int b = idx / (L_ENC*kC*kN);
    float v;
    if (l == 0)          v = X[(((size_t)b*kT + t)*kN + m)*kC + c];
    else if (l < 1 + kH) v = Ht[((size_t)(b*kN + m)*kC + c)*kH + (l - 1)];
    else                 v = featr[m*kF + (l - 1 - kH)];
    XH[idx] = v;
}

// XH = [Hd | Hd | featx] for decoder (deco_in == Hd)
__global__ __launch_bounds__(256) void k_build_xh_dec(
    const float* __restrict__ Ht, const float* __restrict__ featr, float* __restrict__ XH)
{
    int idx = blockIdx.x * blockDim.x + threadIdx.x;
    if (idx >= kB*kN*kC*L_DEC) return;
    int l = idx % L_DEC;
    int c = (idx / L_DEC) % kC;
    int m = (idx / (L_DEC*kC)) % kN;
    int b = idx / (L_DEC*kC*kN);
    size_t hbase = ((size_t)(b*kN + m)*kC + c)*kH;
    float v;
    if (l < kH)        v = Ht[hbase + l];
    else if (l < 2*kH) v = Ht[hbase + (l - kH)];
    else               v = featr[m*kF + (l - 2*kH)];
    XH[idx] = v;
}

// Fused t2 + reshape + gate GEMM + sigmoid; writes upd and CI=[Xt | reset*Ht | featx]
template<int L, int XLEN>
__global__ __launch_bounds__(256) void k_gates(
    const float* __restrict__ XH, const float* __restrict__ Yb,
    const float* __restrict__ GcM, const float* __restrict__ gW, const float* __restrict__ gb,
    const float* __restrict__ Ht, float* __restrict__ upd, float* __restrict__ CI)
{
    constexpr int KJL  = kKS * kKC * L;
    constexpr int CL   = kC * L;
    constexpr int BNCL = kB * kN * CL;
    __shared__ float Ys[3 * CL];
    __shared__ float fs[kC * KJL];
    __shared__ float GcS[64];
    int tid = threadIdx.x;
    int bm  = blockIdx.x;                // b*N + m
    size_t base = (size_t)bm * CL;
    for (int r = tid; r < CL; r += 256) {
        Ys[r]        = XH[base + r];
        Ys[CL + r]   = Yb[base + r];
        Ys[2*CL + r] = Yb[(size_t)BNCL + base + r];
    }
    if (tid < 64) GcS[tid] = GcM[tid];
    __syncthreads();
    for (int e = tid; e < kC * KJL; e += 256) {
        int d = e / KJL, q = e - d*KJL;
        int k = q / (kKC*L); int rr = q - k*(kKC*L); int j = rr / L; int l = rr - j*L;
        float v;
        if (j == 0) v = Ys[k*CL + d*L + l];
        else {
            v = 0.f;
#pragma unroll
            for (int c2 = 0; c2 < kC; ++c2) v += Ys[k*CL + c2*L + l] * GcS[c2*8 + d];
        }
        fs[e] = v;
    }
    __syncthreads();
    int d = tid >> 5, o4 = (tid & 31) * 4;
    const float* fsd = fs + d * KJL;
    float a0 = 0, a1 = 0, a2 = 0, a3 = 0;
    for (int q = 0; q < KJL; ++q) {
        float f = fsd[q];
        float4 w = *(const float4*)&gW[(size_t)q*128 + o4];
        a0 += f*w.x; a1 += f*w.y; a2 += f*w.z; a3 += f*w.w;
    }
    size_t sb = (size_t)bm * kC + d;
    float acc4[4] = {a0, a1, a2, a3};
#pragma unroll
    for (int jj = 0; jj < 4; ++jj) {
        int o = o4 + jj;
        float g = sigm(acc4[jj] + gb[o]);
        if (o < kH) upd[sb*kH + o] = g;
        else { int h = o - kH; CI[sb*L + XLEN + h] = g * Ht[sb*kH + h]; }
    }
    for (int r = tid; r < CL; r += 256) {
        int l = r % L;
        if (l < XLEN || l >= XLEN + kH) CI[base + r] = Ys[r];
    }
}

// Fused t2 + cand GEMM + tanh + state update: Ht = (1-u)*Ht + u*tanh(cand)
template<int L>
__global__ __launch_bounds__(256) void k_cand(
    const float* __restrict__ CIin, const float* __restrict__ Yb,
    const float* __restrict__ GcM, const float* __restrict__ cW, const float* __restrict__ cb,
    const float* __restrict__ upd, float* __restrict__ Ht)
{
    constexpr int KJL  = kKS * kKC * L;
    constexpr int CL   = kC * L;
    constexpr int BNCL = kB * kN * CL;
    __shared__ float Ys[3 * CL];
    __shared__ float fs[kC * KJL];
    __shared__ float GcS[64];
    int tid = threadIdx.x;
    int bm  = blockIdx.x;
    size_t base = (size_t)bm * CL;
    for (int r = tid; r < CL; r += 256) {
        Ys[r]        = CIin[base + r];
        Ys[CL + r]   = Yb[base + r];
        Ys[2*CL + r] = Yb[(size_t)BNCL + base + r];
    }
    if (tid < 64) GcS[tid] = GcM[tid];
    __syncthreads();
    for (int e = tid; e < kC * KJL; e += 256) {
        int d = e / KJL, q = e - d*KJL;
        int k = q / (kKC*L); int rr = q - k*(kKC*L); int j = rr / L; int l = rr - j*L;
        float v;
        if (j == 0) v = Ys[k*CL + d*L + l];
        else {
            v = 0.f;
#pragma unroll
            for (int c2 = 0; c2 < kC; ++c2) v += Ys[k*CL + c2*L + l] * GcS[c2*8 + d];
        }
        fs[e] = v;
    }
    __syncthreads();
    int d = tid >> 5, o2 = (tid & 31) * 2;
    const float* fsd = fs + d * KJL;
    float a0 = 0, a1 = 0;
    for (int q = 0; q < KJL; ++q) {
        float f = fsd[q];
        float2 w = *(const float2*)&cW[(size_t)q*kH + o2];
        a0 += f*w.x; a1 += f*w.y;
    }
    size_t sb = (size_t)bm * kC + d;
#pragma unroll
    for (int jj = 0; jj < 2; ++jj) {
        int h = o2 + jj;
        float cv = tanhf((jj ? a1 : a0) + cb[h]);
        float u  = upd[sb*kH + h];
        float ho = Ht[sb*kH + h];
        Ht[sb*kH + h] = (1.f - u)*ho + u*cv;
    }
}

// out[b,hz,m,c] = relu(Hd @ w1 + b1) @ w2 + b2
__global__ __launch_bounds__(256) void k_outmlp(
    const float* __restrict__ Hd, const float* __restrict__ w1, const float* __restrict__ b1,
    const float* __restrict__ w2, const float* __restrict__ b2, float* __restrict__ out, int hz)
{
    int idx = blockIdx.x * blockDim.x + threadIdx.x;
    if (idx >= kB*kN*kC) return;
    int c = idx % kC; int m = (idx / kC) % kN; int b = idx / (kC*kN);
    const float* h = Hd + (size_t)idx * kH;
    float hreg[kH];
#pragma unroll
    for (int k = 0; k < kH; ++k) hreg[k] = h[k];
    float acc = b2[0];
    for (int e = 0; e < kE; ++e) {
        float s = b1[e];
#pragma unroll
        for (int k = 0; k < kH; ++k) s += hreg[k] * w1[k*kE + e];
        acc += fmaxf(s, 0.f) * w2[e];
    }
    out[((size_t)(b*kHOR + hz)*kN + m)*kC + c] = acc;
}

// ---------------- host ----------------
extern "C" void kernel_launch(void* const* d_in, const int* in_sizes, int n_in,
                              void* d_out, int out_size, void* d_ws, size_t ws_size,
                              hipStream_t stream)
{
    (void)in_sizes; (void)n_in; (void)out_size; (void)ws_size;
    const float* X      = (const float*)d_in[0];
    const float* As     = (const float*)d_in[1];
    const float* Ac     = (const float*)d_in[2];
    const float* featr  = (const float*)d_in[3];
    const float* WuS    = (const float*)d_in[4];
    const float* WvS    = (const float*)d_in[5];
    const float* WuC    = (const float*)d_in[6];
    const float* WvC    = (const float*)d_in[7];
    const float* mfS_w1 = (const float*)d_in[8];
    const float* mfS_b1 = (const float*)d_in[9];
    const float* mfS_w2 = (const float*)d_in[10];
    const float* mfS_b2 = (const float*)d_in[11];
    const float* mfC_w1 = (const float*)d_in[12];
    const float* mfC_b1 = (const float*)d_in[13];
    const float* mfC_w2 = (const float*)d_in[14];
    const float* mfC_b2 = (const float*)d_in[15];
    const float* enc_gW = (const float*)d_in[16];
    const float* enc_gb = (const float*)d_in[17];
    const float* enc_cW = (const float*)d_in[18];
    const float* enc_cb = (const float*)d_in[19];
    const float* dec_gW = (const float*)d_in[20];
    const float* dec_gb = (const float*)d_in[21];
    const float* dec_cW = (const float*)d_in[22];
    const float* dec_cb = (const float*)d_in[23];
    const float* out_w1 = (const float*)d_in[24];
    const float* out_b1 = (const float*)d_in[25];
    const float* out_w2 = (const float*)d_in[26];
    const float* out_b2 = (const float*)d_in[27];
    float* out = (float*)d_out;
    float* ws = (float*)d_ws;

    // persistent arena (floats). Total ~12.06M floats ~46 MB.
    float* Gs   = ws;                    // 262144
    float* Gs2  = Gs  + 262144;          // 262144
    float* Gc   = Gs2 + 262144;          // 256 (64 used)
    float* nfS  = Gc  + 256;             // 1024
    float* AnS  = nfS + 1024;
    float* PnS  = AnS + 1024;
    float* nfC  = PnS + 1024;            // 256 (16 used)
    float* AnC  = nfC + 256;
    float* PnC  = AnC + 256;
    float* Mc   = PnC + 256;             // 256 (64 used)
    float* Pc   = Mc  + 256;             // 256 (64 used)
    float* Htb  = Pc  + 256;             // 1048576
    float* updb = Htb + 1048576;         // 1048576
    float* XHb  = updb + 1048576;        // 2359296
    float* CIb  = XHb + 2359296;         // 2359296
    float* Yb   = CIb + 2359296;         // 4718592
    // phase-1 aliases (dead before GRU starts)
    float* Upr  = XHb;
    float* Vpr  = CIb;
    float* Ms   = Yb;
    float* Ps   = Yb + 262144;
    float* hidA = Yb + 524288;
    float* hidP = Yb + 655360;
    float* keyS = Yb + 786432;
    float* valS = Yb + 917504;
    float* Uc   = Yb + 1048576;
    float* Vc   = Yb + 1060864;
    float* hidAc= Yb + 1073152;
    float* hidPc= Yb + 1075200;
    float* keyC = Yb + 1077248;
    float* valC = Yb + 1079296;

    constexpr int CL_ENC = kC * L_ENC;   // 648
    constexpr int CL_DEC = kC * L_DEC;   // 1152

    hipMemsetAsync(Htb, 0, (size_t)kB*kN*kC*kH*sizeof(float), stream);

    // ---- phase 1: spatial graph ----
    k_uvproj_s<<<(kN*kBT*kH + 255)/256, 256, 0, stream>>>(X, WuS, WvS, Upr, Vpr);
    k_gemm_nt<<<dim3(8, 8), 256, 0, stream>>>(Upr, Vpr, Ms, kN, kN, kRK, 0, nullptr, nullptr);
    k_softmax_pm<<<kN, 256, 0, stream>>>(Ms, Ps, kN);
    k_nf<<<kN, 256, 0, stream>>>(As, Ps, nfS, kN);
    k_anpn<<<kN, 256, 0, stream>>>(As, Ps, nfS, AnS, PnS, kN);
    k_mlp1<<<(kN*256 + 255)/256, 256, 0, stream>>>(AnS, PnS, mfS_w1, mfS_b1, 0, 1, hidA, hidP, kN);
    k_gemm_nn_dual<<<dim3(4, 8), 256, 0, stream>>>(hidA, mfS_w2, hidP, mfS_w2 + 65536,
                                                   mfS_b2, mfS_b2 + 256, keyS, kN, 256, 256);
    k_mlp1<<<(kN*256 + 255)/256, 256, 0, stream>>>(AnS, PnS, mfS_w1, mfS_b1, 2, 3, hidA, hidP, kN);
    k_gemm_nn_dual<<<dim3(4, 8), 256, 0, stream>>>(hidA, mfS_w2 + 2*65536, hidP, mfS_w2 + 3*65536,
                                                   mfS_b2 + 512, mfS_b2 + 768, valS, kN, 256, 256);
    k_gemm_nt<<<dim3(8, 8), 256, 0, stream>>>(keyS, valS, Gs, kN, kN, 256, 1, As, Ps);
    k_cheby<<<dim3(8, 8), 256, 0, stream>>>(Gs, Gs2);

    // ---- phase 1: categorical graph ----
    k_uvproj_c<<<(kBT*kC*kH + 255)/256, 256, 0, stream>>>(X, WuC, WvC, Uc, Vc);
    k_mc<<<1, 64, 0, stream>>>(Uc, Vc, Mc);
    k_softmax_pm<<<kC, 256, 0, stream>>>(Mc, Pc, kC);
    k_nf<<<kC, 256, 0, stream>>>(Ac, Pc, nfC, kC);
    k_anpn<<<kC, 256, 0, stream>>>(Ac, Pc, nfC, AnC, PnC, kC);
    k_mlp1<<<(kC*256 + 255)/256, 256, 0, stream>>>(AnC, PnC, mfC_w1, mfC_b1, 0, 1, hidAc, hidPc, kC);
    k_gemm_nn_dual<<<dim3(4, 1), 256, 0, stream>>>(hidAc, mfC_w2, hidPc, mfC_w2 + 65536,
                                                   mfC_b2, mfC_b2 + 256, keyC, kC, 256, 256);
    k_mlp1<<<(kC*256 + 255)/256, 256, 0, stream>>>(AnC, PnC, mfC_w1, mfC_b1, 2, 3, hidAc, hidPc, kC);
    k_gemm_nn_dual<<<dim3(4, 1), 256, 0, stream>>>(hidAc, mfC_w2 + 2*65536, hidPc, mfC_w2 + 3*65536,
                                                   mfC_b2 + 512, mfC_b2 + 768, valC, kC, 256, 256);
    k_gemm_nt<<<dim3(1, 1), 256, 0, stream>>>(keyC, valC, Gc, kC, kC, 256, 1, Ac, Pc);

    // ---- encoder ----
    for (int t = 0; t < kT; ++t) {
        k_build_xh_enc<<<(kB*kN*kC*L_ENC + 255)/256, 256, 0, stream>>>(X, t, Htb, featr, XHb);
        k_gemm_t1<<<dim3((CL_ENC + 63)/64, 8, 8), 256, 0, stream>>>(Gs, Gs2, XHb, Yb, CL_ENC);
        k_gates<L_ENC, 1><<<kB*kN, 256, 0, stream>>>(XHb, Yb, Gc, enc_gW, enc_gb, Htb, updb, CIb);
        k_gemm_t1<<<dim3((CL_ENC + 63)/64, 8, 8), 256, 0, stream>>>(Gs, Gs2, CIb, Yb, CL_ENC);
        k_cand<L_ENC><<<kB*kN, 256, 0, stream>>>(CIb, Yb, Gc, enc_cW, enc_cb, updb, Htb);
    }

    // ---- decoder ----
    for (int hz = 0; hz < kHOR; ++hz) {
        k_build_xh_dec<<<(kB*kN*kC*L_DEC + 255)/256, 256, 0, stream>>>(Htb, featr, XHb);
        k_gemm_t1<<<dim3((CL_DEC + 63)/64, 8, 8), 256, 0, stream>>>(Gs, Gs2, XHb, Yb, CL_DEC);
        k_gates<L_DEC, kH><<<kB*kN, 256, 0, stream>>>(XHb, Yb, Gc, dec_gW, dec_gb, Htb, updb, CIb);
        k_gemm_t1<<<dim3((CL_DEC + 63)/64, 8, 8), 256, 0, stream>>>(Gs, Gs2, CIb, Yb, CL_DEC);
        k_cand<L_DEC><<<kB*kN, 256, 0, stream>>>(CIb, Yb, Gc, dec_cW, dec_cb, updb, Htb);
        k_outmlp<<<(kB*kN*kC + 255)/256, 256, 0, stream>>>(Htb, out_w1, out_b1, out_w2, out_b2, out, hz);
    }
}

// Round 2
// 1421.738 us; speedup vs baseline: 3.1888x; 3.1888x over previous
//
#include <hip/hip_runtime.h>
#include <math.h>

// ---------------- problem constants ----------------
constexpr int kB = 4, kT = 6, kN = 512, kC = 8;
constexpr int kH = 64, kF = 16, kE = 32;
constexpr int kKS = 3, kKC = 2, kHOR = 3;
constexpr int kBT = kB * kT;          // 24
constexpr int kRK = kBT * kH;         // 1536
constexpr int L_ENC = 1 + kH + kF;    // 81
constexpr int L_DEC = kH + kH + kF;   // 144
constexpr int PL_ENC = 96;            // 81 padded to 3*32
constexpr int PL_DEC = 160;           // 144 padded to 5*32
constexpr int KP_ENC = 3 * PL_ENC;    // 288
constexpr int KP_DEC = 3 * PL_DEC;    // 480
constexpr float kALPHA = 3.0f;

typedef unsigned short ushortT;
typedef short short8 __attribute__((ext_vector_type(8)));
typedef float f32x4 __attribute__((ext_vector_type(4)));

__device__ __forceinline__ float sigm(float x) { return 1.0f / (1.0f + __expf(-x)); }

__device__ __forceinline__ ushortT f2bf(float f) {
    union { float f; unsigned int u; } v; v.f = f;
    unsigned int r = v.u + 0x7fffu + ((v.u >> 16) & 1u);
    return (ushortT)(r >> 16);
}
__device__ __forceinline__ float bf2f(ushortT b) {
    union { unsigned int u; float f; } v; v.u = ((unsigned int)b) << 16; return v.f;
}

__device__ __forceinline__ void fma44(const float4& a, const float4& b, float acc[4][4]) {
    acc[0][0] += a.x*b.x; acc[0][1] += a.x*b.y; acc[0][2] += a.x*b.z; acc[0][3] += a.x*b.w;
    acc[1][0] += a.y*b.x; acc[1][1] += a.y*b.y; acc[1][2] += a.y*b.z; acc[1][3] += a.y*b.w;
    acc[2][0] += a.z*b.x; acc[2][1] += a.z*b.y; acc[2][2] += a.z*b.z; acc[2][3] += a.z*b.w;
    acc[3][0] += a.w*b.x; acc[3][1] += a.w*b.y; acc[3][2] += a.w*b.z; acc[3][3] += a.w*b.w;
}

// ---------------- phase 1: adaptive graph (f32, unchanged) ----------------

__global__ __launch_bounds__(256) void k_uvproj_s(
    const float* __restrict__ X, const float* __restrict__ Wu, const float* __restrict__ Wv,
    float* __restrict__ Upr, float* __restrict__ Vpr)
{
    int idx = blockIdx.x * blockDim.x + threadIdx.x;
    if (idx >= kN * kBT * kH) return;
    int h = idx % kH; int bt = (idx / kH) % kBT; int n = idx / (kH * kBT);
    const float* xr = X + ((size_t)bt * kN + n) * kC;
    float u = 0.f, v = 0.f;
#pragma unroll
    for (int c = 0; c < kC; ++c) { float x = xr[c]; u += x * Wu[c*kH + h]; v += x * Wv[c*kH + h]; }
    Upr[(size_t)n * kRK + bt * kH + h] = tanhf(kALPHA * u);
    Vpr[(size_t)n * kRK + bt * kH + h] = tanhf(kALPHA * v);
}

__global__ __launch_bounds__(256) void k_uvproj_c(
    const float* __restrict__ X, const float* __restrict__ WuC, const float* __restrict__ WvC,
    float* __restrict__ Uc, float* __restrict__ Vc)
{
    int idx = blockIdx.x * blockDim.x + threadIdx.x;
    if (idx >= kBT * kC * kH) return;
    int h = idx % kH; int c = (idx / kH) % kC; int bt = idx / (kH * kC);
    const float* xb = X + (size_t)bt * kN * kC + c;
    float u = 0.f, v = 0.f;
    for (int n = 0; n < kN; ++n) { float x = xb[n*kC]; u += x * WuC[n*kH + h]; v += x * WvC[n*kH + h]; }
    Uc[(bt*kC + c)*kH + h] = tanhf(kALPHA * u);
    Vc[(bt*kC + c)*kH + h] = tanhf(kALPHA * v);
}

__global__ void k_mc(const float* __restrict__ Uc, const float* __restrict__ Vc, float* __restrict__ Mc)
{
    int t = threadIdx.x; if (t >= 64) return;
    int d = t % 8, c = t / 8;
    float s = 0.f;
    for (int bt = 0; bt < kBT; ++bt)
        for (int h = 0; h < kH; ++h)
            s += Uc[(bt*8 + c)*kH + h] * Vc[(bt*8 + d)*kH + h];
    Mc[c*8 + d] = s;
}

__global__ __launch_bounds__(256) void k_softmax_pm(const float* __restrict__ M, float* __restrict__ P, int S)
{
    int i = blockIdx.x, tid = threadIdx.x;
    __shared__ float sm[256];
    float mx = -1e30f;
    for (int j = tid; j < S; j += 256) {
        float v = fmaxf(M[(size_t)i*S + j] - M[(size_t)j*S + i], 0.f);
        mx = fmaxf(mx, v);
    }
    sm[tid] = mx; __syncthreads();
    for (int s = 128; s > 0; s >>= 1) { if (tid < s) sm[tid] = fmaxf(sm[tid], sm[tid+s]); __syncthreads(); }
    mx = sm[0]; __syncthreads();
    float sum = 0.f;
    for (int j = tid; j < S; j += 256) {
        float v = fmaxf(M[(size_t)i*S + j] - M[(size_t)j*S + i], 0.f);
        float e = __expf(v - mx);
        P[(size_t)i*S + j] = e; sum += e;
    }
    sm[tid] = sum; __syncthreads();
    for (int s = 128; s > 0; s >>= 1) { if (tid < s) sm[tid] += sm[tid+s]; __syncthreads(); }
    float inv = 1.f / sm[0];
    __syncthreads();
    for (int j = tid; j < S; j += 256) P[(size_t)i*S + j] *= inv;
}

__global__ __launch_bounds__(256) void k_nf(const float* __restrict__ A, const float* __restrict__ P,
                                            float* __restrict__ nf, int S)
{
    int i = blockIdx.x, tid = threadIdx.x;
    __shared__ float sa[256], sp[256];
    float a = 0.f, p = 0.f;
    for (int j = tid; j < S; j += 256) { a += A[(size_t)i*S + j]; p += P[(size_t)i*S + j]; }
    sa[tid] = a; sp[tid] = p; __syncthreads();
    for (int s = 128; s > 0; s >>= 1) { if (tid < s) { sa[tid] += sa[tid+s]; sp[tid] += sp[tid+s]; } __syncthreads(); }
    if (!tid) { nf[i*2] = sa[0]; nf[i*2+1] = sp[0]; }
}

__global__ __launch_bounds__(256) void k_anpn(const float* __restrict__ A, const float* __restrict__ P,
                                              const float* __restrict__ nf,
                                              float* __restrict__ An, float* __restrict__ Pn, int S)
{
    int i = blockIdx.x, tid = threadIdx.x;
    __shared__ float s0[256], s1[256], s2[256], s3[256];
    float a0 = 0, a1 = 0, p0 = 0, p1 = 0;
    for (int j = tid; j < S; j += 256) {
        float av = A[(size_t)i*S + j], pv = P[(size_t)i*S + j];
        float n0 = nf[2*j], n1 = nf[2*j + 1];
        a0 += av*n0; a1 += av*n1; p0 += pv*n0; p1 += pv*n1;
    }
    s0[tid]=a0; s1[tid]=a1; s2[tid]=p0; s3[tid]=p1; __syncthreads();
    for (int s = 128; s > 0; s >>= 1) {
        if (tid < s) { s0[tid]+=s0[tid+s]; s1[tid]+=s1[tid+s]; s2[tid]+=s2[tid+s]; s3[tid]+=s3[tid+s]; }
        __syncthreads();
    }
    if (!tid) { An[i*2]=s0[0]; An[i*2+1]=s1[0]; Pn[i*2]=s2[0]; Pn[i*2+1]=s3[0]; }
}

__global__ __launch_bounds__(256) void k_mlp1(
    const float* __restrict__ An, const float* __restrict__ Pn,
    const float* __restrict__ w1, const float* __restrict__ b1, int ia, int ip,
    float* __restrict__ hidA, float* __restrict__ hidP, int M)
{
    int idx = blockIdx.x * blockDim.x + threadIdx.x;
    if (idx >= M * 256) return;
    int o = idx % 256, i = idx / 256;
    const float* w1a = w1 + (size_t)ia * 512; const float* b1a = b1 + (size_t)ia * 256;
    const float* w1p = w1 + (size_t)ip * 512; const float* b1p = b1 + (size_t)ip * 256;
    float a = An[i*2] * w1a[o] + An[i*2+1] * w1a[256 + o] + b1a[o];
    float p = Pn[i*2] * w1p[o] + Pn[i*2+1] * w1p[256 + o] + b1p[o];
    hidA[(size_t)i*256 + o] = fmaxf(a, 0.f);
    hidP[(size_t)i*256 + o] = fmaxf(p, 0.f);
}

__global__ __launch_bounds__(256) void k_gemm_nt(
    const float* __restrict__ A, const float* __restrict__ Bm, float* __restrict__ Cm,
    int M, int Ncols, int K, int mode,
    const float* __restrict__ Apr, const float* __restrict__ Ppr)
{
    __shared__ __align__(16) float sA[16][68];
    __shared__ __align__(16) float sB[16][68];
    int tid = threadIdx.x, tx = tid & 15, ty = tid >> 4;
    int i0 = blockIdx.y * 64, j0 = blockIdx.x * 64;
    float acc[4][4] = {};
    for (int k0 = 0; k0 < K; k0 += 16) {
#pragma unroll
        for (int it = 0; it < 4; ++it) {
            int r = tid + it * 256;
            int kk = r & 15, ii = r >> 4;
            int gi = i0 + ii, gj = j0 + ii;
            sA[kk][ii] = (gi < M)     ? A[(size_t)gi*K + k0 + kk]  : 0.f;
            sB[kk][ii] = (gj < Ncols) ? Bm[(size_t)gj*K + k0 + kk] : 0.f;
        }
        __syncthreads();
#pragma unroll
        for (int kk = 0; kk < 16; ++kk) {
            float4 a = *(const float4*)&sA[kk][ty*4];
            float4 b = *(const float4*)&sB[kk][tx*4];
            fma44(a, b, acc);
        }
        __syncthreads();
    }
#pragma unroll
    for (int i = 0; i < 4; ++i) {
        int gi = i0 + ty*4 + i; if (gi >= M) continue;
#pragma unroll
        for (int j = 0; j < 4; ++j) {
            int gj = j0 + tx*4 + j; if (gj >= Ncols) continue;
            float v = acc[i][j];
            if (mode == 1) {
                float s = sigm(v);
                v = s * Apr[(size_t)gi*Ncols + gj] + (1.f - s) * Ppr[(size_t)gi*Ncols + gj];
            }
            Cm[(size_t)gi*Ncols + gj] = v;
        }
    }
}

__global__ __launch_bounds__(256) void k_gemm_nn_dual(
    const float* __restrict__ A1, const float* __restrict__ B1,
    const float* __restrict__ A2, const float* __restrict__ B2,
    const float* __restrict__ bias1, const float* __restrict__ bias2,
    float* __restrict__ Cm, int M, int Ncols, int K)
{
    __shared__ __align__(16) float sA[16][68];
    __shared__ __align__(16) float sB[16][68];
    int tid = threadIdx.x, tx = tid & 15, ty = tid >> 4;
    int i0 = blockIdx.y * 64, j0 = blockIdx.x * 64;
    float acc[4][4] = {};
    for (int kq = 0; kq < 2*K; kq += 16) {
        const float* Aq; const float* Bq; int k0;
        if (kq < K) { Aq = A1; Bq = B1; k0 = kq; } else { Aq = A2; Bq = B2; k0 = kq - K; }
#pragma unroll
        for (int it = 0; it < 4; ++it) {
            int r = tid + it * 256;
            int kk = r & 15, ii = r >> 4;
            int gi = i0 + ii;
            sA[kk][ii] = (gi < M) ? Aq[(size_t)gi*K + k0 + kk] : 0.f;
        }
#pragma unroll
        for (int it = 0; it < 4; ++it) {
            int r = tid + it * 256;
            int jj = r & 63, kk = r >> 6;
            int gj = j0 + jj;
            sB[kk][jj] = (gj < Ncols) ? Bq[(size_t)(k0 + kk)*Ncols + gj] : 0.f;
        }
        __syncthreads();
#pragma unroll
        for (int kk = 0; kk < 16; ++kk) {
            float4 a = *(const float4*)&sA[kk][ty*4];
            float4 b = *(const float4*)&sB[kk][tx*4];
            fma44(a, b, acc);
        }
        __syncthreads();
    }
#pragma unroll
    for (int i = 0; i < 4; ++i) {
        int gi = i0 + ty*4 + i; if (gi >= M) continue;
#pragma unroll
        for (int j = 0; j < 4; ++j) {
            int gj = j0 + tx*4 + j; if (gj >= Ncols) continue;
            Cm[(size_t)gi*Ncols + gj] = acc[i][j] + bias1[gj] + bias2[gj];
        }
    }
}

__global__ __launch_bounds__(256) void k_cheby(const float* __restrict__ G, float* __restrict__ G2)
{
    __shared__ __align__(16) float sA[16][68];
    __shared__ __align__(16) float sB[16][68];
    int tid = threadIdx.x, tx = tid & 15, ty = tid >> 4;
    int i0 = blockIdx.y * 64, j0 = blockIdx.x * 64;
    float acc[4][4] = {};
    for (int k0 = 0; k0 < kN; k0 += 16) {
#pragma unroll
        for (int it = 0; it < 4; ++it) {
            int r = tid + it * 256;
            int kk = r & 15, ii = r >> 4;
            sA[kk][ii] = G[(size_t)(i0 + ii)*kN + k0 + kk];
        }
#pragma unroll
        for (int it = 0; it < 4; ++it) {
            int r = tid + it * 256;
            int jj = r & 63, kk = r >> 6;
            sB[kk][jj] = G[(size_t)(k0 + kk)*kN + j0 + jj];
        }
        __syncthreads();
#pragma unroll
        for (int kk = 0; kk < 16; ++kk) {
            float4 a = *(const float4*)&sA[kk][ty*4];
            float4 b = *(const float4*)&sB[kk][tx*4];
            fma44(a, b, acc);
        }
        __syncthreads();
    }
#pragma unroll
    for (int i = 0; i < 4; ++i) {
        int gi = i0 + ty*4 + i;
#pragma unroll
        for (int j = 0; j < 4; ++j) {
            int gj = j0 + tx*4 + j;
            G2[(size_t)gi*kN + gj] = 2.f * acc[i][j] - (gi == gj ? 1.f : 0.f);
        }
    }
}

// ---------------- bf16 preps ----------------

// Gt[i][j] = bf16(G[j][i]), 512x512
__global__ void k_transp(const float* __restrict__ G, ushortT* __restrict__ Gt)
{
    __shared__ float tile[32][33];
    int bx = blockIdx.x * 32, by = blockIdx.y * 32;
    int x = threadIdx.x, y0 = threadIdx.y;
    for (int yy = y0; yy < 32; yy += 8) tile[yy][x] = G[(size_t)(by+yy)*kN + bx + x];
    __syncthreads();
    for (int yy = y0; yy < 32; yy += 8) Gt[(size_t)(bx+yy)*kN + by + x] = f2bf(tile[x][yy]);
}

// WT[o][kk*PL + l] = W[((kk*2 + j)*L + l)*outW + oo], j = o/outW, oo = o%outW; 0 if l>=L
__global__ __launch_bounds__(256) void k_prep_wt(
    const float* __restrict__ W, ushortT* __restrict__ WT,
    int L, int PL, int KP, int outW)
{
    int idx = blockIdx.x * blockDim.x + threadIdx.x;
    if (idx >= 2 * outW * KP) return;
    int qp = idx % KP, o = idx / KP;
    int kk = qp / PL, l = qp - kk * PL;
    int j = o / outW, oo = o - j * outW;
    float v = (l < L) ? W[(size_t)((kk*2 + j)*L + l) * outW + oo] : 0.f;
    WT[idx] = f2bf(v);
}

// ---------------- MFMA GEMMs ----------------

// Y[ki,b] = Gst_ki @ Xslab_b, all 512 x CLP, bf16 in/out, CLP in {768, 1280}
template<int CLP>
__global__ __launch_bounds__(256) void k_t1_mfma(
    const ushortT* __restrict__ Gst, const ushortT* __restrict__ Xin, ushortT* __restrict__ Yout)
{
    __shared__ short sA[128][40];
    __shared__ short sB[128][40];   // [col][k]
    int tid = threadIdx.x;
    int ki = blockIdx.z >> 2, b = blockIdx.z & 3;
    const ushortT* A = Gst + (size_t)ki * kN * kN;
    const ushortT* B = Xin + (size_t)b * kN * CLP;
    ushortT* C = Yout + (size_t)(ki*4 + b) * kN * CLP;
    int m0 = blockIdx.y * 128, j0 = blockIdx.x * 128;
    int w = tid >> 6, lane = tid & 63, wr = w >> 1, wc = w & 1;
    f32x4 acc[4][4];
#pragma unroll
    for (int i = 0; i < 4; ++i)
#pragma unroll
        for (int j = 0; j < 4; ++j) acc[i][j] = (f32x4){0.f, 0.f, 0.f, 0.f};

    for (int k0 = 0; k0 < kN; k0 += 32) {
        {   // A-tile: 128 rows x 32 k, row-major
            int row = tid >> 1, lc = (tid & 1) * 16;
            const ushortT* p = A + (size_t)(m0 + row)*kN + k0 + lc;
            *(short8*)&sA[row][lc]     = *(const short8*)p;
            *(short8*)&sA[row][lc + 8] = *(const short8*)(p + 8);
        }
        {   // B-tile: 32 k x 128 cols, store transposed sB[col][k]
            int kr = tid & 31, jc = (tid >> 5) * 8;
#pragma unroll
            for (int rep = 0; rep < 2; ++rep) {
                short8 v = *(const short8*)(B + (size_t)(k0 + kr)*CLP + j0 + jc + rep*64);
#pragma unroll
                for (int i = 0; i < 8; ++i) sB[jc + rep*64 + i][kr] = v[i];
            }
        }
        __syncthreads();
        short8 af[4], bfr[4];
#pragma unroll
        for (int mi = 0; mi < 4; ++mi)
            af[mi] = *(const short8*)&sA[wr*64 + mi*16 + (lane & 15)][(lane >> 4) * 8];
#pragma unroll
        for (int ni = 0; ni < 4; ++ni)
            bfr[ni] = *(const short8*)&sB[wc*64 + ni*16 + (lane & 15)][(lane >> 4) * 8];
#pragma unroll
        for (int mi = 0; mi < 4; ++mi)
#pragma unroll
            for (int ni = 0; ni < 4; ++ni)
                acc[mi][ni] = __builtin_amdgcn_mfma_f32_16x16x32_bf16(af[mi], bfr[ni], acc[mi][ni], 0, 0, 0);
        __syncthreads();
    }
#pragma unroll
    for (int mi = 0; mi < 4; ++mi) {
#pragma unroll
        for (int ni = 0; ni < 4; ++ni) {
            int row = m0 + wr*64 + mi*16 + (lane >> 4) * 4;
            int col = j0 + wc*64 + ni*16 + (lane & 15);
#pragma unroll
            for (int q = 0; q < 4; ++q)
                C[(size_t)(row + q)*CLP + col] = f2bf(acc[mi][ni][q]);
        }
    }
}

// C[16384 x Ntot] = A_gather[16384 x KP] @ WT^T, A gathered from XH(k=0) and Yb(k=1,2)
// FN: 4 -> BN=128 (gates, Ntot=256), 2 -> BN=64 (cand, Ntot=128)
template<int PL, int KP, int FN>
__global__ __launch_bounds__(256) void k_gg_mfma(
    const ushortT* __restrict__ XH, const ushortT* __restrict__ Yb,
    const ushortT* __restrict__ WT, float* __restrict__ Cout, int Ntot)
{
    constexpr int BN = 32 * FN;
    __shared__ short sA[128][40];
    __shared__ short sB[BN][40];    // [col][k]
    int tid = threadIdx.x;
    int r0 = blockIdx.y * 128, j0 = blockIdx.x * BN;
    int b = r0 >> 12, rr = r0 & 4095;
    const ushortT* src0 = XH + (size_t)r0 * PL;
    const ushortT* src1 = Yb + ((size_t)b       * 4096 + rr) * PL;
    const ushortT* src2 = Yb + ((size_t)(4 + b) * 4096 + rr) * PL;
    int w = tid >> 6, lane = tid & 63, wr = w >> 1, wc = w & 1;
    f32x4 acc[4][FN];
#pragma unroll
    for (int i = 0; i < 4; ++i)
#pragma unroll
        for (int j = 0; j < FN; ++j) acc[i][j] = (f32x4){0.f, 0.f, 0.f, 0.f};

    for (int k0 = 0; k0 < KP; k0 += 32) {
        int kk = k0 / PL;
        int l0 = k0 - kk * PL;
        const ushortT* A = (kk == 0) ? src0 : (kk == 1) ? src1 : src2;
        {   // A-tile
            int row = tid >> 1, lc = (tid & 1) * 16;
            const ushortT* p = A + (size_t)row * PL + l0 + lc;
            *(short8*)&sA[row][lc]     = *(const short8*)p;
            *(short8*)&sA[row][lc + 8] = *(const short8*)(p + 8);
        }
        // B-tile from pre-transposed WT [Ntot][KP]: contiguous along k
        if (FN == 4) {
            int col = tid >> 1, seg = (tid & 1) * 16;
            const ushortT* p = WT + (size_t)(j0 + col)*KP + k0 + seg;
            *(short8*)&sB[col][seg]     = *(const short8*)p;
            *(short8*)&sB[col][seg + 8] = *(const short8*)(p + 8);
        } else {
            int col = tid >> 2, seg = (tid & 3) * 8;
            *(short8*)&sB[col][seg] = *(const short8*)(WT + (size_t)(j0 + col)*KP + k0 + seg);
        }
        __syncthreads();
        short8 af[4], bfr[FN];
#pragma unroll
        for (int mi = 0; mi < 4; ++mi)
            af[mi] = *(const short8*)&sA[wr*64 + mi*16 + (lane & 15)][(lane >> 4) * 8];
#pragma unroll
        for (int ni = 0; ni < FN; ++ni)
            bfr[ni] = *(const short8*)&sB[wc*16*FN + ni*16 + (lane & 15)][(lane >> 4) * 8];
#pragma unroll
        for (int mi = 0; mi < 4; ++mi)
#pragma unroll
            for (int ni = 0; ni < FN; ++ni)
                acc[mi][ni] = __builtin_amdgcn_mfma_f32_16x16x32_bf16(af[mi], bfr[ni], acc[mi][ni], 0, 0, 0);
        __syncthreads();
    }
#pragma unroll
    for (int mi = 0; mi < 4; ++mi) {
#pragma unroll
        for (int ni = 0; ni < FN; ++ni) {
            int row = r0 + wr*64 + mi*16 + (lane >> 4) * 4;
            int col = j0 + wc*16*FN + ni*16 + (lane & 15);
#pragma unroll
            for (int q = 0; q < 4; ++q)
                Cout[(size_t)(row + q)*Ntot + col] = acc[mi][ni][q];
        }
    }
}

// ---------------- GRU cell builds / epilogues ----------------

__global__ __launch_bounds__(256) void k_build_enc(
    const float* __restrict__ X, int t, const float* __restrict__ Ht,
    const float* __restrict__ featr, ushortT* __restrict__ XH)
{
    int idx = blockIdx.x * blockDim.x + threadIdx.x;
    if (idx >= 16384 * PL_ENC) return;
    int l = idx % PL_ENC; int r = idx / PL_ENC;
    int c = r & 7; int m = (r >> 3) & 511; int b = r >> 12;
    float v;
    if (l == 0)            v = X[(((size_t)b*kT + t)*kN + m)*kC + c];
    else if (l < 1 + kH)   v = Ht[(size_t)r*kH + l - 1];
    else if (l < L_ENC)    v = featr[m*kF + l - 1 - kH];
    else                   v = 0.f;
    XH[idx] = f2bf(v);
}

__global__ __launch_bounds__(256) void k_build_dec(
    const float* __restrict__ Ht, const float* __restrict__ featr, ushortT* __restrict__ XH)
{
    int idx = blockIdx.x * blockDim.x + threadIdx.x;
    if (idx >= 16384 * PL_DEC) return;
    int l = idx % PL_DEC; int r = idx / PL_DEC;
    int m = (r >> 3) & 511;
    float v;
    if (l < kH)            v = Ht[(size_t)r*kH + l];
    else if (l < 2*kH)     v = Ht[(size_t)r*kH + l - kH];
    else if (l < L_DEC)    v = featr[m*kF + l - 2*kH];
    else                   v = 0.f;
    XH[idx] = f2bf(v);
}

// gates epilogue: Gg [16384][256] = [G1 | T]; pre = G1[d][o] + sum_c Gc[c][d]*T[c][o] + gb[o]
// o<64 -> upd; o>=64 -> reset -> CI middle (in-place in XH, bf16)
template<int PL, int XLEN>
__global__ __launch_bounds__(256) void k_gates_ep(
    const float* __restrict__ Gg, const float* __restrict__ GcM,
    const float* __restrict__ gb, const float* __restrict__ Ht,
    float* __restrict__ upd, ushortT* __restrict__ XH)
{
    __shared__ float sG[8][256];
    __shared__ float GcS[64];
    int tid = threadIdx.x, bm = blockIdx.x;
    const float* src = Gg + (size_t)bm * 8 * 256;
    for (int i = tid; i < 2048; i += 256) sG[i >> 8][i & 255] = src[i];
    if (tid < 64) GcS[tid] = GcM[tid];
    __syncthreads();
    int d = tid >> 5, o0 = (tid & 31) * 4;
    size_t rb = (size_t)bm * 8 + d;
#pragma unroll
    for (int q = 0; q < 4; ++q) {
        int o = o0 + q;
        float pre = sG[d][o] + gb[o];
#pragma unroll
        for (int c = 0; c < 8; ++c) pre += GcS[c*8 + d] * sG[c][128 + o];
        float g = sigm(pre);
        if (o < kH) upd[rb*kH + o] = g;
        else {
            int h = o - kH;
            XH[rb*PL + XLEN + h] = f2bf(g * Ht[rb*kH + h]);
        }
    }
}

// cand epilogue: Gc2 [16384][128] = [C1 | Tc]; Ht = (1-u)*Ht + u*tanh(pre)
__global__ __launch_bounds__(256) void k_cand_ep(
    const float* __restrict__ Gc2, const float* __restrict__ GcM,
    const float* __restrict__ cb, const float* __restrict__ upd, float* __restrict__ Ht)
{
    __shared__ float sG[8][128];
    __shared__ float GcS[64];
    int tid = threadIdx.x, bm = blockIdx.x;
    const float* src = Gc2 + (size_t)bm * 8 * 128;
    for (int i = tid; i < 1024; i += 256) sG[i >> 7][i & 127] = src[i];
    if (tid < 64) GcS[tid] = GcM[tid];
    __syncthreads();
    int d = tid >> 5, o0 = (tid & 31) * 2;
    size_t rb = (size_t)bm * 8 + d;
#pragma unroll
    for (int q = 0; q < 2; ++q) {
        int o = o0 + q;
        float pre = sG[d][o] + cb[o];
#pragma unroll
        for (int c = 0; c < 8; ++c) pre += GcS[c*8 + d] * sG[c][64 + o];
        float cv = tanhf(pre);
        float u = upd[rb*kH + o];
        float h0 = Ht[rb*kH + o];
        Ht[rb*kH + o] = (1.f - u)*h0 + u*cv;
    }
}

__global__ __launch_bounds__(256) void k_outmlp(
    const float* __restrict__ Hd, const float* __restrict__ w1, const float* __restrict__ b1,
    const float* __restrict__ w2, const float* __restrict__ b2, float* __restrict__ out, int hz)
{
    int idx = blockIdx.x * blockDim.x + threadIdx.x;
    if (idx >= kB*kN*kC) return;
    int c = idx % kC; int m = (idx / kC) % kN; int b = idx / (kC*kN);
    const float* h = Hd + (size_t)idx * kH;
    float hreg[kH];
#pragma unroll
    for (int k = 0; k < kH; ++k) hreg[k] = h[k];
    float acc = b2[0];
    for (int e = 0; e < kE; ++e) {
        float s = b1[e];
#pragma unroll
        for (int k = 0; k < kH; ++k) s += hreg[k] * w1[k*kE + e];
        acc += fmaxf(s, 0.f) * w2[e];
    }
    out[((size_t)(b*kHOR + hz)*kN + m)*kC + c] = acc;
}

// ---------------- host ----------------
extern "C" void kernel_launch(void* const* d_in, const int* in_sizes, int n_in,
                              void* d_out, int out_size, void* d_ws, size_t ws_size,
                              hipStream_t stream)
{
    (void)in_sizes; (void)n_in; (void)out_size; (void)ws_size;
    const float* X      = (const float*)d_in[0];
    const float* As     = (const float*)d_in[1];
    const float* Ac     = (const float*)d_in[2];
    const float* featr  = (const float*)d_in[3];
    const float* WuS    = (const float*)d_in[4];
    const float* WvS    = (const float*)d_in[5];
    const float* WuC    = (const float*)d_in[6];
    const float* WvC    = (const float*)d_in[7];
    const float* mfS_w1 = (const float*)d_in[8];
    const float* mfS_b1 = (const float*)d_in[9];
    const float* mfS_w2 = (const float*)d_in[10];
    const float* mfS_b2 = (const float*)d_in[11];
    const float* mfC_w1 = (const float*)d_in[12];
    const float* mfC_b1 = (const float*)d_in[13];
    const float* mfC_w2 = (const float*)d_in[14];
    const float* mfC_b2 = (const float*)d_in[15];
    const float* enc_gW = (const float*)d_in[16];
    const float* enc_gb = (const float*)d_in[17];
    const float* enc_cW = (const float*)d_in[18];
    const float* enc_cb = (const float*)d_in[19];
    const float* dec_gW = (const float*)d_in[20];
    const float* dec_gb = (const float*)d_in[21];
    const float* dec_cW = (const float*)d_in[22];
    const float* dec_cb = (const float*)d_in[23];
    const float* out_w1 = (const float*)d_in[24];
    const float* out_b1 = (const float*)d_in[25];
    const float* out_w2 = (const float*)d_in[26];
    const float* out_b2 = (const float*)d_in[27];
    float* out = (float*)d_out;
    float* ws = (float*)d_ws;

    // ---- arena (floats) ----
    float* Ht     = ws;                      // 1,048,576
    float* updb   = Ht + 1048576;            // 1,048,576
    float* Gg     = updb + 1048576;          // 4,194,304 (GEMM out + phase1 alias)
    float* Gs     = Gg + 4194304;            // 262,144
    float* Gs2    = Gs + 262144;             // 262,144
    float* smallf = Gs2 + 262144;            // 8,192
    float* nfS = smallf;
    float* AnS = nfS + 1024;
    float* PnS = AnS + 1024;
    float* nfC = PnS + 1024;
    float* AnC = nfC + 64;
    float* PnC = AnC + 64;
    float* McB = PnC + 64;
    float* PcB = McB + 64;
    float* GcF = PcB + 64;
    ushortT* XHb  = (ushortT*)(smallf + 8192);   // 16384*160 = 2,621,440
    ushortT* Yb   = XHb + 2621440;               // 2 * 2,621,440
    ushortT* GstB = Yb + 5242880;                // 2 * 262,144
    ushortT* WTg_e = GstB + 524288;              // 73,728
    ushortT* WTc_e = WTg_e + 73728;              // 36,864
    ushortT* WTg_d = WTc_e + 36864;              // 122,880
    ushortT* WTc_d = WTg_d + 122880;             // 61,440
    // phase-1 aliases inside Gg
    float* Upr  = Gg;
    float* Vpr  = Upr + 786432;
    float* Ms   = Vpr + 786432;
    float* Ps   = Ms + 262144;
    float* hidA = Ps + 262144;
    float* hidP = hidA + 131072;
    float* keyS = hidP + 131072;
    float* valS = keyS + 131072;
    float* Uc   = valS + 131072;
    float* Vc   = Uc + 12288;
    float* hidAc = Vc + 12288;
    float* hidPc = hidAc + 2048;
    float* keyC  = hidPc + 2048;
    float* valC  = keyC + 2048;

    constexpr int CLP_ENC = kC * PL_ENC;   // 768
    constexpr int CLP_DEC = kC * PL_DEC;   // 1280

    hipMemsetAsync(Ht, 0, (size_t)16384 * kH * sizeof(float), stream);

    // ---- weight preps (independent of phase 1) ----
    k_prep_wt<<<(2*128*KP_ENC + 255)/256, 256, 0, stream>>>(enc_gW, WTg_e, L_ENC, PL_ENC, KP_ENC, 128);
    k_prep_wt<<<(2*64 *KP_ENC + 255)/256, 256, 0, stream>>>(enc_cW, WTc_e, L_ENC, PL_ENC, KP_ENC, 64);
    k_prep_wt<<<(2*128*KP_DEC + 255)/256, 256, 0, stream>>>(dec_gW, WTg_d, L_DEC, PL_DEC, KP_DEC, 128);
    k_prep_wt<<<(2*64 *KP_DEC + 255)/256, 256, 0, stream>>>(dec_cW, WTc_d, L_DEC, PL_DEC, KP_DEC, 64);

    // ---- phase 1: spatial graph ----
    k_uvproj_s<<<(kN*kBT*kH + 255)/256, 256, 0, stream>>>(X, WuS, WvS, Upr, Vpr);
    k_gemm_nt<<<dim3(8, 8), 256, 0, stream>>>(Upr, Vpr, Ms, kN, kN, kRK, 0, nullptr, nullptr);
    k_softmax_pm<<<kN, 256, 0, stream>>>(Ms, Ps, kN);
    k_nf<<<kN, 256, 0, stream>>>(As, Ps, nfS, kN);
    k_anpn<<<kN, 256, 0, stream>>>(As, Ps, nfS, AnS, PnS, kN);
    k_mlp1<<<(kN*256 + 255)/256, 256, 0, stream>>>(AnS, PnS, mfS_w1, mfS_b1, 0, 1, hidA, hidP, kN);
    k_gemm_nn_dual<<<dim3(4, 8), 256, 0, stream>>>(hidA, mfS_w2, hidP, mfS_w2 + 65536,
                                                   mfS_b2, mfS_b2 + 256, keyS, kN, 256, 256);
    k_mlp1<<<(kN*256 + 255)/256, 256, 0, stream>>>(AnS, PnS, mfS_w1, mfS_b1, 2, 3, hidA, hidP, kN);
    k_gemm_nn_dual<<<dim3(4, 8), 256, 0, stream>>>(hidA, mfS_w2 + 2*65536, hidP, mfS_w2 + 3*65536,
                                                   mfS_b2 + 512, mfS_b2 + 768, valS, kN, 256, 256);
    k_gemm_nt<<<dim3(8, 8), 256, 0, stream>>>(keyS, valS, Gs, kN, kN, 256, 1, As, Ps);
    k_cheby<<<dim3(8, 8), 256, 0, stream>>>(Gs, Gs2);
    k_transp<<<dim3(16, 16), dim3(32, 8), 0, stream>>>(Gs, GstB);
    k_transp<<<dim3(16, 16), dim3(32, 8), 0, stream>>>(Gs2, GstB + 262144);

    // ---- phase 1: categorical graph ----
    k_uvproj_c<<<(kBT*kC*kH + 255)/256, 256, 0, stream>>>(X, WuC, WvC, Uc, Vc);
    k_mc<<<1, 64, 0, stream>>>(Uc, Vc, McB);
    k_softmax_pm<<<kC, 256, 0, stream>>>(McB, PcB, kC);
    k_nf<<<kC, 256, 0, stream>>>(Ac, PcB, nfC, kC);
    k_anpn<<<kC, 256, 0, stream>>>(Ac, PcB, nfC, AnC, PnC, kC);
    k_mlp1<<<(kC*256 + 255)/256, 256, 0, stream>>>(AnC, PnC, mfC_w1, mfC_b1, 0, 1, hidAc, hidPc, kC);
    k_gemm_nn_dual<<<dim3(4, 1), 256, 0, stream>>>(hidAc, mfC_w2, hidPc, mfC_w2 + 65536,
                                                   mfC_b2, mfC_b2 + 256, keyC, kC, 256, 256);
    k_mlp1<<<(kC*256 + 255)/256, 256, 0, stream>>>(AnC, PnC, mfC_w1, mfC_b1, 2, 3, hidAc, hidPc, kC);
    k_gemm_nn_dual<<<dim3(4, 1), 256, 0, stream>>>(hidAc, mfC_w2 + 2*65536, hidPc, mfC_w2 + 3*65536,
                                                   mfC_b2 + 512, mfC_b2 + 768, valC, kC, 256, 256);
    k_gemm_nt<<<dim3(1, 1), 256, 0, stream>>>(keyC, valC, GcF, kC, kC, 256, 1, Ac, PcB);

    // ---- encoder ----
    for (int t = 0; t < kT; ++t) {
        k_build_enc<<<(16384*PL_ENC + 255)/256, 256, 0, stream>>>(X, t, Ht, featr, XHb);
        k_t1_mfma<CLP_ENC><<<dim3(CLP_ENC/128, 4, 8), 256, 0, stream>>>(GstB, XHb, Yb);
        k_gg_mfma<PL_ENC, KP_ENC, 4><<<dim3(2, 128), 256, 0, stream>>>(XHb, Yb, WTg_e, Gg, 256);
        k_gates_ep<PL_ENC, 1><<<2048, 256, 0, stream>>>(Gg, GcF, enc_gb, Ht, updb, XHb);
        k_t1_mfma<CLP_ENC><<<dim3(CLP_ENC/128, 4, 8), 256, 0, stream>>>(GstB, XHb, Yb);
        k_gg_mfma<PL_ENC, KP_ENC, 2><<<dim3(2, 128), 256, 0, stream>>>(XHb, Yb, WTc_e, Gg, 128);
        k_cand_ep<<<2048, 256, 0, stream>>>(Gg, GcF, enc_cb, updb, Ht);
    }

    // ---- decoder ----
    for (int hz = 0; hz < kHOR; ++hz) {
        k_build_dec<<<(16384*PL_DEC + 255)/256, 256, 0, stream>>>(Ht, featr, XHb);
        k_t1_mfma<CLP_DEC><<<dim3(CLP_DEC/128, 4, 8), 256, 0, stream>>>(GstB, XHb, Yb);
        k_gg_mfma<PL_DEC, KP_DEC, 4><<<dim3(2, 128), 256, 0, stream>>>(XHb, Yb, WTg_d, Gg, 256);
        k_gates_ep<PL_DEC, kH><<<2048, 256, 0, stream>>>(Gg, GcF, dec_gb, Ht, updb, XHb);
        k_t1_mfma<CLP_DEC><<<dim3(CLP_DEC/128, 4, 8), 256, 0, stream>>>(GstB, XHb, Yb);
        k_gg_mfma<PL_DEC, KP_DEC, 2><<<dim3(2, 128), 256, 0, stream>>>(XHb, Yb, WTc_d, Gg, 128);
        k_cand_ep<<<2048, 256, 0, stream>>>(Gg, GcF, dec_cb, updb, Ht);
        k_outmlp<<<(kB*kN*kC + 255)/256, 256, 0, stream>>>(Ht, out_w1, out_b1, out_w2, out_b2, out, hz);
    }
}

// Round 3
// 1021.603 us; speedup vs baseline: 4.4378x; 1.3917x over previous
//
#include <hip/hip_runtime.h>
#include <math.h>

// ---------------- problem constants ----------------
constexpr int kB = 4, kT = 6, kN = 512, kC = 8;
constexpr int kH = 64, kF = 16, kE = 32;
constexpr int kKS = 3, kKC = 2, kHOR = 3;
constexpr int kBT = kB * kT;          // 24
constexpr int kRK = kBT * kH;         // 1536
constexpr int L_ENC = 1 + kH + kF;    // 81
constexpr int L_DEC = kH + kH + kF;   // 144
constexpr int PL_ENC = 96;            // 81 padded to 3*32
constexpr int PL_DEC = 160;           // 144 padded to 5*32
constexpr int KP_ENC = 3 * PL_ENC;    // 288
constexpr int KP_DEC = 3 * PL_DEC;    // 480
constexpr float kALPHA = 3.0f;

typedef unsigned short ushortT;
typedef short short8 __attribute__((ext_vector_type(8)));
typedef float f32x4 __attribute__((ext_vector_type(4)));

__device__ __forceinline__ float sigm(float x) { return 1.0f / (1.0f + __expf(-x)); }

__device__ __forceinline__ ushortT f2bf(float f) {
    union { float f; unsigned int u; } v; v.f = f;
    unsigned int r = v.u + 0x7fffu + ((v.u >> 16) & 1u);
    return (ushortT)(r >> 16);
}

__device__ __forceinline__ void fma44(const float4& a, const float4& b, float acc[4][4]) {
    acc[0][0] += a.x*b.x; acc[0][1] += a.x*b.y; acc[0][2] += a.x*b.z; acc[0][3] += a.x*b.w;
    acc[1][0] += a.y*b.x; acc[1][1] += a.y*b.y; acc[1][2] += a.y*b.z; acc[1][3] += a.y*b.w;
    acc[2][0] += a.z*b.x; acc[2][1] += a.z*b.y; acc[2][2] += a.z*b.z; acc[2][3] += a.z*b.w;
    acc[3][0] += a.w*b.x; acc[3][1] += a.w*b.y; acc[3][2] += a.w*b.z; acc[3][3] += a.w*b.w;
}

// ---------------- phase 1: projections ----------------

__global__ __launch_bounds__(256) void k_uvproj_s(
    const float* __restrict__ X, const float* __restrict__ Wu, const float* __restrict__ Wv,
    float* __restrict__ Upr, float* __restrict__ Vpr)
{
    int idx = blockIdx.x * blockDim.x + threadIdx.x;
    if (idx >= kN * kBT * kH) return;
    int h = idx % kH; int bt = (idx / kH) % kBT; int n = idx / (kH * kBT);
    const float* xr = X + ((size_t)bt * kN + n) * kC;
    float u = 0.f, v = 0.f;
#pragma unroll
    for (int c = 0; c < kC; ++c) { float x = xr[c]; u += x * Wu[c*kH + h]; v += x * Wv[c*kH + h]; }
    Upr[(size_t)n * kRK + bt * kH + h] = tanhf(kALPHA * u);
    Vpr[(size_t)n * kRK + bt * kH + h] = tanhf(kALPHA * v);
}

__global__ __launch_bounds__(256) void k_uvproj_c(
    const float* __restrict__ X, const float* __restrict__ WuC, const float* __restrict__ WvC,
    float* __restrict__ Uc, float* __restrict__ Vc)
{
    int idx = blockIdx.x * blockDim.x + threadIdx.x;
    if (idx >= kBT * kC * kH) return;
    int h = idx % kH; int c = (idx / kH) % kC; int bt = idx / (kH * kC);
    const float* xb = X + (size_t)bt * kN * kC + c;
    float u = 0.f, v = 0.f;
    for (int n = 0; n < kN; ++n) { float x = xb[n*kC]; u += x * WuC[n*kH + h]; v += x * WvC[n*kH + h]; }
    Uc[(bt*kC + c)*kH + h] = tanhf(kALPHA * u);
    Vc[(bt*kC + c)*kH + h] = tanhf(kALPHA * v);
}

__global__ void k_mc(const float* __restrict__ Uc, const float* __restrict__ Vc, float* __restrict__ Mc)
{
    int t = threadIdx.x; if (t >= 64) return;
    int d = t % 8, c = t / 8;
    float s = 0.f;
    for (int bt = 0; bt < kBT; ++bt)
        for (int h = 0; h < kH; ++h)
            s += Uc[(bt*8 + c)*kH + h] * Vc[(bt*8 + d)*kH + h];
    Mc[c*8 + d] = s;
}

__global__ __launch_bounds__(256) void k_softmax_pm(const float* __restrict__ M, float* __restrict__ P, int S)
{
    int i = blockIdx.x, tid = threadIdx.x;
    __shared__ float sm[256];
    float mx = -1e30f;
    for (int j = tid; j < S; j += 256) {
        float v = fmaxf(M[(size_t)i*S + j] - M[(size_t)j*S + i], 0.f);
        mx = fmaxf(mx, v);
    }
    sm[tid] = mx; __syncthreads();
    for (int s = 128; s > 0; s >>= 1) { if (tid < s) sm[tid] = fmaxf(sm[tid], sm[tid+s]); __syncthreads(); }
    mx = sm[0]; __syncthreads();
    float sum = 0.f;
    for (int j = tid; j < S; j += 256) {
        float v = fmaxf(M[(size_t)i*S + j] - M[(size_t)j*S + i], 0.f);
        float e = __expf(v - mx);
        P[(size_t)i*S + j] = e; sum += e;
    }
    sm[tid] = sum; __syncthreads();
    for (int s = 128; s > 0; s >>= 1) { if (tid < s) sm[tid] += sm[tid+s]; __syncthreads(); }
    float inv = 1.f / sm[0];
    __syncthreads();
    for (int j = tid; j < S; j += 256) P[(size_t)i*S + j] *= inv;
}

__global__ __launch_bounds__(256) void k_nf(const float* __restrict__ A, const float* __restrict__ P,
                                            float* __restrict__ nf, int S)
{
    int i = blockIdx.x, tid = threadIdx.x;
    __shared__ float sa[256], sp[256];
    float a = 0.f, p = 0.f;
    for (int j = tid; j < S; j += 256) { a += A[(size_t)i*S + j]; p += P[(size_t)i*S + j]; }
    sa[tid] = a; sp[tid] = p; __syncthreads();
    for (int s = 128; s > 0; s >>= 1) { if (tid < s) { sa[tid] += sa[tid+s]; sp[tid] += sp[tid+s]; } __syncthreads(); }
    if (!tid) { nf[i*2] = sa[0]; nf[i*2+1] = sp[0]; }
}

__global__ __launch_bounds__(256) void k_anpn(const float* __restrict__ A, const float* __restrict__ P,
                                              const float* __restrict__ nf,
                                              float* __restrict__ An, float* __restrict__ Pn, int S)
{
    int i = blockIdx.x, tid = threadIdx.x;
    __shared__ float s0[256], s1[256], s2[256], s3[256];
    float a0 = 0, a1 = 0, p0 = 0, p1 = 0;
    for (int j = tid; j < S; j += 256) {
        float av = A[(size_t)i*S + j], pv = P[(size_t)i*S + j];
        float n0 = nf[2*j], n1 = nf[2*j + 1];
        a0 += av*n0; a1 += av*n1; p0 += pv*n0; p1 += pv*n1;
    }
    s0[tid]=a0; s1[tid]=a1; s2[tid]=p0; s3[tid]=p1; __syncthreads();
    for (int s = 128; s > 0; s >>= 1) {
        if (tid < s) { s0[tid]+=s0[tid+s]; s1[tid]+=s1[tid+s]; s2[tid]+=s2[tid+s]; s3[tid]+=s3[tid+s]; }
        __syncthreads();
    }
    if (!tid) { An[i*2]=s0[0]; An[i*2+1]=s1[0]; Pn[i*2]=s2[0]; Pn[i*2+1]=s3[0]; }
}

// hidAP[i][col]: col<256 -> relu(An@w1[ia]+b1[ia]); col>=256 -> relu(Pn@w1[ip]+b1[ip])
__global__ __launch_bounds__(256) void k_mlp1cat(
    const float* __restrict__ An, const float* __restrict__ Pn,
    const float* __restrict__ w1, const float* __restrict__ b1, int ia, int ip,
    float* __restrict__ hidAP)
{
    int idx = blockIdx.x * 256 + threadIdx.x;
    if (idx >= 512 * 512) return;
    int col = idx & 511, i = idx >> 9;
    float v;
    if (col < 256) {
        const float* w = w1 + (size_t)ia * 512; const float* b = b1 + (size_t)ia * 256;
        v = An[i*2]*w[col] + An[i*2+1]*w[256 + col] + b[col];
    } else {
        int o = col - 256;
        const float* w = w1 + (size_t)ip * 512; const float* b = b1 + (size_t)ip * 256;
        v = Pn[i*2]*w[o] + Pn[i*2+1]*w[256 + o] + b[o];
    }
    hidAP[idx] = fmaxf(v, 0.f);
}

// w2tK[n][kk] = kk<256 ? w2[0][kk][n] : w2[1][kk-256][n] ; w2tV same with slices 2,3
__global__ __launch_bounds__(256) void k_prep_w2t(
    const float* __restrict__ w2, float* __restrict__ w2tK, float* __restrict__ w2tV)
{
    int idx = blockIdx.x * 256 + threadIdx.x;
    if (idx >= 256 * 512) return;
    int kk = idx & 511, n = idx >> 9;
    int j = kk >> 8, k = kk & 255;
    w2tK[idx] = w2[(size_t)(0 + j)*65536 + k*256 + n];
    w2tV[idx] = w2[(size_t)(2 + j)*65536 + k*256 + n];
}

// ---------------- generic split-K f32 NT GEMM ----------------
// part[sk][M][N] = A[M, krange] * B[N, krange]^T ; M,N multiples of 64, skl multiple of 32
__global__ __launch_bounds__(256) void k_gemm_ntsk(
    const float* __restrict__ A, const float* __restrict__ B, float* __restrict__ part,
    int M, int N, int K, int skl)
{
    __shared__ __align__(16) float sA[32][68];
    __shared__ __align__(16) float sB[32][68];
    int tid = threadIdx.x, tx = tid & 15, ty = tid >> 4;
    int j0 = blockIdx.x * 64, i0 = blockIdx.y * 64;
    int kb = blockIdx.z * skl;
    float acc[4][4] = {};
    for (int k0 = kb; k0 < kb + skl; k0 += 32) {
#pragma unroll
        for (int it = 0; it < 2; ++it) {
            int q = tid + it * 256;
            int row = q >> 3, ks = (q & 7) * 4;
            float4 va = *(const float4*)&A[(size_t)(i0 + row)*K + k0 + ks];
            float4 vb = *(const float4*)&B[(size_t)(j0 + row)*K + k0 + ks];
            sA[ks+0][row] = va.x; sA[ks+1][row] = va.y; sA[ks+2][row] = va.z; sA[ks+3][row] = va.w;
            sB[ks+0][row] = vb.x; sB[ks+1][row] = vb.y; sB[ks+2][row] = vb.z; sB[ks+3][row] = vb.w;
        }
        __syncthreads();
#pragma unroll
        for (int kk = 0; kk < 32; ++kk) {
            float4 a = *(const float4*)&sA[kk][ty*4];
            float4 b = *(const float4*)&sB[kk][tx*4];
            fma44(a, b, acc);
        }
        __syncthreads();
    }
    float* dst = part + (size_t)blockIdx.z * M * N;
#pragma unroll
    for (int i = 0; i < 4; ++i)
#pragma unroll
        for (int j = 0; j < 4; ++j)
            dst[(size_t)(i0 + ty*4 + i)*N + j0 + tx*4 + j] = acc[i][j];
}

// reduce partials + epilogue. mode 0: plain; 1: s=sigm(sum), C=s*p1+(1-s)*p2 (p1/p2 [M][N]);
// 2: C = sum + p1[col] + p2[col]
__global__ __launch_bounds__(256) void k_redep(
    const float* __restrict__ part, int SK, int total, int N,
    float* __restrict__ C, int mode,
    const float* __restrict__ p1, const float* __restrict__ p2)
{
    int idx = blockIdx.x * 256 + threadIdx.x;
    if (idx >= total) return;
    float s = 0.f;
    for (int k = 0; k < SK; ++k) s += part[(size_t)k*total + idx];
    if (mode == 1) { float a = sigm(s); s = a*p1[idx] + (1.f - a)*p2[idx]; }
    else if (mode == 2) { int col = idx % N; s += p1[col] + p2[col]; }
    C[idx] = s;
}

// ---------------- categorical fused MLP chain ----------------
// grid (2 kv, 4 colchunk); keyval [2][8][256]
__global__ __launch_bounds__(256) void k_catmlp(
    const float* __restrict__ AnC, const float* __restrict__ PnC,
    const float* __restrict__ w1, const float* __restrict__ b1,
    const float* __restrict__ w2, const float* __restrict__ b2,
    float* __restrict__ keyval)
{
    __shared__ float hA[8][256], hP[8][256];
    int tid = threadIdx.x;
    int kv = blockIdx.x, c0 = blockIdx.y * 64;
    int qa = kv*2, qp = kv*2 + 1;
    for (int e = tid; e < 2048; e += 256) {
        int i = e >> 8, o = e & 255;
        hA[i][o] = fmaxf(AnC[i*2]*w1[qa*512 + o] + AnC[i*2+1]*w1[qa*512 + 256 + o] + b1[qa*256 + o], 0.f);
        hP[i][o] = fmaxf(PnC[i*2]*w1[qp*512 + o] + PnC[i*2+1]*w1[qp*512 + 256 + o] + b1[qp*256 + o], 0.f);
    }
    __syncthreads();
    for (int e = tid; e < 512; e += 256) {
        int i = e >> 6, oc = c0 + (e & 63);
        float s = b2[qa*256 + oc] + b2[qp*256 + oc];
        for (int k = 0; k < 256; ++k)
            s += hA[i][k]*w2[(size_t)qa*65536 + k*256 + oc] + hP[i][k]*w2[(size_t)qp*65536 + k*256 + oc];
        keyval[(size_t)kv*2048 + i*256 + oc] = s;
    }
}

__global__ void k_gcfuse(const float* __restrict__ keyval, const float* __restrict__ Ac,
                         const float* __restrict__ Pc, float* __restrict__ GcF)
{
    int t = threadIdx.x; if (t >= 64) return;
    int c = t >> 3, d = t & 7;
    const float* key = keyval;
    const float* val = keyval + 2048;
    float s = 0.f;
    for (int k = 0; k < 256; ++k) s += key[c*256 + k] * val[d*256 + k];
    float a = sigm(s);
    GcF[c*8 + d] = a*Ac[c*8 + d] + (1.f - a)*Pc[c*8 + d];
}

// ---------------- bf16 preps ----------------

__global__ void k_transp(const float* __restrict__ G, ushortT* __restrict__ Gt)
{
    __shared__ float tile[32][33];
    int bx = blockIdx.x * 32, by = blockIdx.y * 32;
    int x = threadIdx.x, y0 = threadIdx.y;
    for (int yy = y0; yy < 32; yy += 8) tile[yy][x] = G[(size_t)(by+yy)*kN + bx + x];
    __syncthreads();
    for (int yy = y0; yy < 32; yy += 8) Gt[(size_t)(bx+yy)*kN + by + x] = f2bf(tile[x][yy]);
}

__global__ __launch_bounds__(256) void k_prep_wt(
    const float* __restrict__ W, ushortT* __restrict__ WT,
    int L, int PL, int KP, int outW)
{
    int idx = blockIdx.x * blockDim.x + threadIdx.x;
    if (idx >= 2 * outW * KP) return;
    int qp = idx % KP, o = idx / KP;
    int kk = qp / PL, l = qp - kk * PL;
    int j = o / outW, oo = o - j * outW;
    float v = (l < L) ? W[(size_t)((kk*2 + j)*L + l) * outW + oo] : 0.f;
    WT[idx] = f2bf(v);
}

// Gst2 = 2 * Gst @ Gst - I   (bf16 in/out, f32 acc; equals bf16((2 Gs@Gs - I)^T))
__global__ __launch_bounds__(256) void k_cheby_mfma(
    const ushortT* __restrict__ Gst, ushortT* __restrict__ Gst2)
{
    __shared__ short sA[128][40];
    __shared__ short sB[128][40];
    int tid = threadIdx.x;
    int m0 = blockIdx.y * 128, j0 = blockIdx.x * 128;
    int w = tid >> 6, lane = tid & 63, wr = w >> 1, wc = w & 1;
    f32x4 acc[4][4];
#pragma unroll
    for (int i = 0; i < 4; ++i)
#pragma unroll
        for (int j = 0; j < 4; ++j) acc[i][j] = (f32x4){0.f, 0.f, 0.f, 0.f};
    for (int k0 = 0; k0 < kN; k0 += 32) {
        {
            int row = tid >> 1, lc = (tid & 1) * 16;
            const ushortT* p = Gst + (size_t)(m0 + row)*kN + k0 + lc;
            *(short8*)&sA[row][lc]     = *(const short8*)p;
            *(short8*)&sA[row][lc + 8] = *(const short8*)(p + 8);
        }
        {
            int kr = tid & 31, jc = (tid >> 5) * 8;
#pragma unroll
            for (int rep = 0; rep < 2; ++rep) {
                short8 v = *(const short8*)(Gst + (size_t)(k0 + kr)*kN + j0 + jc + rep*64);
#pragma unroll
                for (int i = 0; i < 8; ++i) sB[jc + rep*64 + i][kr] = v[i];
            }
        }
        __syncthreads();
        short8 af[4], bfr[4];
#pragma unroll
        for (int mi = 0; mi < 4; ++mi)
            af[mi] = *(const short8*)&sA[wr*64 + mi*16 + (lane & 15)][(lane >> 4) * 8];
#pragma unroll
        for (int ni = 0; ni < 4; ++ni)
            bfr[ni] = *(const short8*)&sB[wc*64 + ni*16 + (lane & 15)][(lane >> 4) * 8];
#pragma unroll
        for (int mi = 0; mi < 4; ++mi)
#pragma unroll
            for (int ni = 0; ni < 4; ++ni)
                acc[mi][ni] = __builtin_amdgcn_mfma_f32_16x16x32_bf16(af[mi], bfr[ni], acc[mi][ni], 0, 0, 0);
        __syncthreads();
    }
#pragma unroll
    for (int mi = 0; mi < 4; ++mi) {
#pragma unroll
        for (int ni = 0; ni < 4; ++ni) {
            int row0 = m0 + wr*64 + mi*16 + (lane >> 4) * 4;
            int col  = j0 + wc*64 + ni*16 + (lane & 15);
#pragma unroll
            for (int q = 0; q < 4; ++q) {
                int row = row0 + q;
                Gst2[(size_t)row*kN + col] = f2bf(2.f*acc[mi][ni][q] - (row == col ? 1.f : 0.f));
            }
        }
    }
}

// ---------------- MFMA GEMMs (GRU) ----------------

template<int CLP>
__global__ __launch_bounds__(256) void k_t1_mfma(
    const ushortT* __restrict__ Gst, const ushortT* __restrict__ Xin, ushortT* __restrict__ Yout)
{
    __shared__ short sA[128][40];
    __shared__ short sB[128][40];
    int tid = threadIdx.x;
    int ki = blockIdx.z >> 2, b = blockIdx.z & 3;
    const ushortT* A = Gst + (size_t)ki * kN * kN;
    const ushortT* B = Xin + (size_t)b * kN * CLP;
    ushortT* C = Yout + (size_t)(ki*4 + b) * kN * CLP;
    int m0 = blockIdx.y * 128, j0 = blockIdx.x * 128;
    int w = tid >> 6, lane = tid & 63, wr = w >> 1, wc = w & 1;
    f32x4 acc[4][4];
#pragma unroll
    for (int i = 0; i < 4; ++i)
#pragma unroll
        for (int j = 0; j < 4; ++j) acc[i][j] = (f32x4){0.f, 0.f, 0.f, 0.f};

    for (int k0 = 0; k0 < kN; k0 += 32) {
        {
            int row = tid >> 1, lc = (tid & 1) * 16;
            const ushortT* p = A + (size_t)(m0 + row)*kN + k0 + lc;
            *(short8*)&sA[row][lc]     = *(const short8*)p;
            *(short8*)&sA[row][lc + 8] = *(const short8*)(p + 8);
        }
        {
            int kr = tid & 31, jc = (tid >> 5) * 8;
#pragma unroll
            for (int rep = 0; rep < 2; ++rep) {
                short8 v = *(const short8*)(B + (size_t)(k0 + kr)*CLP + j0 + jc + rep*64);
#pragma unroll
                for (int i = 0; i < 8; ++i) sB[jc + rep*64 + i][kr] = v[i];
            }
        }
        __syncthreads();
        short8 af[4], bfr[4];
#pragma unroll
        for (int mi = 0; mi < 4; ++mi)
            af[mi] = *(const short8*)&sA[wr*64 + mi*16 + (lane & 15)][(lane >> 4) * 8];
#pragma unroll
        for (int ni = 0; ni < 4; ++ni)
            bfr[ni] = *(const short8*)&sB[wc*64 + ni*16 + (lane & 15)][(lane >> 4) * 8];
#pragma unroll
        for (int mi = 0; mi < 4; ++mi)
#pragma unroll
            for (int ni = 0; ni < 4; ++ni)
                acc[mi][ni] = __builtin_amdgcn_mfma_f32_16x16x32_bf16(af[mi], bfr[ni], acc[mi][ni], 0, 0, 0);
        __syncthreads();
    }
#pragma unroll
    for (int mi = 0; mi < 4; ++mi) {
#pragma unroll
        for (int ni = 0; ni < 4; ++ni) {
            int row = m0 + wr*64 + mi*16 + (lane >> 4) * 4;
            int col = j0 + wc*64 + ni*16 + (lane & 15);
#pragma unroll
            for (int q = 0; q < 4; ++q)
                C[(size_t)(row + q)*CLP + col] = f2bf(acc[mi][ni][q]);
        }
    }
}

template<int PL, int KP, int FN>
__global__ __launch_bounds__(256) void k_gg_mfma(
    const ushortT* __restrict__ XH, const ushortT* __restrict__ Yb,
    const ushortT* __restrict__ WT, float* __restrict__ Cout, int Ntot)
{
    constexpr int BN = 32 * FN;
    __shared__ short sA[128][40];
    __shared__ short sB[BN][40];
    int tid = threadIdx.x;
    int r0 = blockIdx.y * 128, j0 = blockIdx.x * BN;
    int b = r0 >> 12, rr = r0 & 4095;
    const ushortT* src0 = XH + (size_t)r0 * PL;
    const ushortT* src1 = Yb + ((size_t)b       * 4096 + rr) * PL;
    const ushortT* src2 = Yb + ((size_t)(4 + b) * 4096 + rr) * PL;
    int w = tid >> 6, lane = tid & 63, wr = w >> 1, wc = w & 1;
    f32x4 acc[4][FN];
#pragma unroll
    for (int i = 0; i < 4; ++i)
#pragma unroll
        for (int j = 0; j < FN; ++j) acc[i][j] = (f32x4){0.f, 0.f, 0.f, 0.f};

    for (int k0 = 0; k0 < KP; k0 += 32) {
        int kk = k0 / PL;
        int l0 = k0 - kk * PL;
        const ushortT* A = (kk == 0) ? src0 : (kk == 1) ? src1 : src2;
        {
            int row = tid >> 1, lc = (tid & 1) * 16;
            const ushortT* p = A + (size_t)row * PL + l0 + lc;
            *(short8*)&sA[row][lc]     = *(const short8*)p;
            *(short8*)&sA[row][lc + 8] = *(const short8*)(p + 8);
        }
        if (FN == 4) {
            int col = tid >> 1, seg = (tid & 1) * 16;
            const ushortT* p = WT + (size_t)(j0 + col)*KP + k0 + seg;
            *(short8*)&sB[col][seg]     = *(const short8*)p;
            *(short8*)&sB[col][seg + 8] = *(const short8*)(p + 8);
        } else {
            int col = tid >> 2, seg = (tid & 3) * 8;
            *(short8*)&sB[col][seg] = *(const short8*)(WT + (size_t)(j0 + col)*KP + k0 + seg);
        }
        __syncthreads();
        short8 af[4], bfr[FN];
#pragma unroll
        for (int mi = 0; mi < 4; ++mi)
            af[mi] = *(const short8*)&sA[wr*64 + mi*16 + (lane & 15)][(lane >> 4) * 8];
#pragma unroll
        for (int ni = 0; ni < FN; ++ni)
            bfr[ni] = *(const short8*)&sB[wc*16*FN + ni*16 + (lane & 15)][(lane >> 4) * 8];
#pragma unroll
        for (int mi = 0; mi < 4; ++mi)
#pragma unroll
            for (int ni = 0; ni < FN; ++ni)
                acc[mi][ni] = __builtin_amdgcn_mfma_f32_16x16x32_bf16(af[mi], bfr[ni], acc[mi][ni], 0, 0, 0);
        __syncthreads();
    }
#pragma unroll
    for (int mi = 0; mi < 4; ++mi) {
#pragma unroll
        for (int ni = 0; ni < FN; ++ni) {
            int row = r0 + wr*64 + mi*16 + (lane >> 4) * 4;
            int col = j0 + wc*16*FN + ni*16 + (lane & 15);
#pragma unroll
            for (int q = 0; q < 4; ++q)
                Cout[(size_t)(row + q)*Ntot + col] = acc[mi][ni][q];
        }
    }
}

// ---------------- GRU cell builds / epilogues ----------------

__global__ __launch_bounds__(256) void k_build_enc(
    const float* __restrict__ X, int t, const float* __restrict__ Ht,
    const float* __restrict__ featr, ushortT* __restrict__ XH)
{
    int idx = blockIdx.x * blockDim.x + threadIdx.x;
    if (idx >= 16384 * PL_ENC) return;
    int l = idx % PL_ENC; int r = idx / PL_ENC;
    int c = r & 7; int m = (r >> 3) & 511; int b = r >> 12;
    float v;
    if (l == 0)            v = X[(((size_t)b*kT + t)*kN + m)*kC + c];
    else if (l < 1 + kH)   v = Ht[(size_t)r*kH + l - 1];
    else if (l < L_ENC)    v = featr[m*kF + l - 1 - kH];
    else                   v = 0.f;
    XH[idx] = f2bf(v);
}

__global__ __launch_bounds__(256) void k_build_dec(
    const float* __restrict__ Ht, const float* __restrict__ featr, ushortT* __restrict__ XH)
{
    int idx = blockIdx.x * blockDim.x + threadIdx.x;
    if (idx >= 16384 * PL_DEC) return;
    int l = idx % PL_DEC; int r = idx / PL_DEC;
    int m = (r >> 3) & 511;
    float v;
    if (l < kH)            v = Ht[(size_t)r*kH + l];
    else if (l < 2*kH)     v = Ht[(size_t)r*kH + l - kH];
    else if (l < L_DEC)    v = featr[m*kF + l - 2*kH];
    else                   v = 0.f;
    XH[idx] = f2bf(v);
}

template<int PL, int XLEN>
__global__ __launch_bounds__(256) void k_gates_ep(
    const float* __restrict__ Gg, const float* __restrict__ GcM,
    const float* __restrict__ gb, const float* __restrict__ Ht,
    float* __restrict__ upd, ushortT* __restrict__ XH)
{
    __shared__ float sG[8][256];
    __shared__ float GcS[64];
    int tid = threadIdx.x, bm = blockIdx.x;
    const float* src = Gg + (size_t)bm * 8 * 256;
    for (int i = tid; i < 2048; i += 256) sG[i >> 8][i & 255] = src[i];
    if (tid < 64) GcS[tid] = GcM[tid];
    __syncthreads();
    int d = tid >> 5, o0 = (tid & 31) * 4;
    size_t rb = (size_t)bm * 8 + d;
#pragma unroll
    for (int q = 0; q < 4; ++q) {
        int o = o0 + q;
        float pre = sG[d][o] + gb[o];
#pragma unroll
        for (int c = 0; c < 8; ++c) pre += GcS[c*8 + d] * sG[c][128 + o];
        float g = sigm(pre);
        if (o < kH) upd[rb*kH + o] = g;
        else {
            int h = o - kH;
            XH[rb*PL + XLEN + h] = f2bf(g * Ht[rb*kH + h]);
        }
    }
}

__global__ __launch_bounds__(256) void k_cand_ep(
    const float* __restrict__ Gc2, const float* __restrict__ GcM,
    const float* __restrict__ cb, const float* __restrict__ upd, float* __restrict__ Ht)
{
    __shared__ float sG[8][128];
    __shared__ float GcS[64];
    int tid = threadIdx.x, bm = blockIdx.x;
    const float* src = Gc2 + (size_t)bm * 8 * 128;
    for (int i = tid; i < 1024; i += 256) sG[i >> 7][i & 127] = src[i];
    if (tid < 64) GcS[tid] = GcM[tid];
    __syncthreads();
    int d = tid >> 5, o0 = (tid & 31) * 2;
    size_t rb = (size_t)bm * 8 + d;
#pragma unroll
    for (int q = 0; q < 2; ++q) {
        int o = o0 + q;
        float pre = sG[d][o] + cb[o];
#pragma unroll
        for (int c = 0; c < 8; ++c) pre += GcS[c*8 + d] * sG[c][64 + o];
        float cv = tanhf(pre);
        float u = upd[rb*kH + o];
        float h0 = Ht[rb*kH + o];
        Ht[rb*kH + o] = (1.f - u)*h0 + u*cv;
    }
}

__global__ __launch_bounds__(256) void k_outmlp(
    const float* __restrict__ Hd, const float* __restrict__ w1, const float* __restrict__ b1,
    const float* __restrict__ w2, const float* __restrict__ b2, float* __restrict__ out, int hz)
{
    int idx = blockIdx.x * blockDim.x + threadIdx.x;
    if (idx >= kB*kN*kC) return;
    int c = idx % kC; int m = (idx / kC) % kN; int b = idx / (kC*kN);
    const float* h = Hd + (size_t)idx * kH;
    float hreg[kH];
#pragma unroll
    for (int k = 0; k < kH; ++k) hreg[k] = h[k];
    float acc = b2[0];
    for (int e = 0; e < kE; ++e) {
        float s = b1[e];
#pragma unroll
        for (int k = 0; k < kH; ++k) s += hreg[k] * w1[k*kE + e];
        acc += fmaxf(s, 0.f) * w2[e];
    }
    out[((size_t)(b*kHOR + hz)*kN + m)*kC + c] = acc;
}

// ---------------- host ----------------
extern "C" void kernel_launch(void* const* d_in, const int* in_sizes, int n_in,
                              void* d_out, int out_size, void* d_ws, size_t ws_size,
                              hipStream_t stream)
{
    (void)in_sizes; (void)n_in; (void)out_size; (void)ws_size;
    const float* X      = (const float*)d_in[0];
    const float* As     = (const float*)d_in[1];
    const float* Ac     = (const float*)d_in[2];
    const float* featr  = (const float*)d_in[3];
    const float* WuS    = (const float*)d_in[4];
    const float* WvS    = (const float*)d_in[5];
    const float* WuC    = (const float*)d_in[6];
    const float* WvC    = (const float*)d_in[7];
    const float* mfS_w1 = (const float*)d_in[8];
    const float* mfS_b1 = (const float*)d_in[9];
    const float* mfS_w2 = (const float*)d_in[10];
    const float* mfS_b2 = (const float*)d_in[11];
    const float* mfC_w1 = (const float*)d_in[12];
    const float* mfC_b1 = (const float*)d_in[13];
    const float* mfC_w2 = (const float*)d_in[14];
    const float* mfC_b2 = (const float*)d_in[15];
    const float* enc_gW = (const float*)d_in[16];
    const float* enc_gb = (const float*)d_in[17];
    const float* enc_cW = (const float*)d_in[18];
    const float* enc_cb = (const float*)d_in[19];
    const float* dec_gW = (const float*)d_in[20];
    const float* dec_gb = (const float*)d_in[21];
    const float* dec_cW = (const float*)d_in[22];
    const float* dec_cb = (const float*)d_in[23];
    const float* out_w1 = (const float*)d_in[24];
    const float* out_b1 = (const float*)d_in[25];
    const float* out_w2 = (const float*)d_in[26];
    const float* out_b2 = (const float*)d_in[27];
    float* out = (float*)d_out;
    float* ws = (float*)d_ws;

    // ---- arena (floats) ----
    float* Ht     = ws;                      // 1,048,576
    float* updb   = Ht + 1048576;            // 1,048,576
    float* Gg     = updb + 1048576;          // 4,194,304 (GRU GEMM out + phase1 aliases)
    float* Gs     = Gg + 4194304;            // 262,144
    float* smallf = Gs + 262144;             // 8,192
    float* nfS = smallf;                     // 1024
    float* AnS = nfS + 1024;                 // 1024
    float* PnS = AnS + 1024;                 // 1024
    float* nfC = PnS + 1024;                 // 64
    float* AnC = nfC + 64;
    float* PnC = AnC + 64;
    float* McB = PnC + 64;
    float* PcB = McB + 64;
    float* GcF = PcB + 64;
    float* kvC = GcF + 64;                   // 4096
    ushortT* XHb  = (ushortT*)(smallf + 8192);   // 16384*160 = 2,621,440
    ushortT* Yb   = XHb + 2621440;               // 5,242,880
    ushortT* GstB = Yb + 5242880;                // 524,288 (Gst + Gst2)
    ushortT* WTg_e = GstB + 524288;              // 73,728
    ushortT* WTc_e = WTg_e + 73728;              // 36,864
    ushortT* WTg_d = WTc_e + 36864;              // 122,880
    ushortT* WTc_d = WTg_d + 122880;             // 61,440
    // phase-1 aliases inside Gg
    float* Upr   = Gg;                       // 786,432
    float* Vpr   = Upr + 786432;             // 786,432
    float* part  = Vpr + 786432;             // 1,048,576 (split-K partials)
    float* Ms    = part + 1048576;           // 262,144
    float* Ps    = Ms + 262144;              // 262,144
    float* hidAP = Ps + 262144;              // 262,144
    float* keyS  = hidAP + 262144;           // 131,072
    float* valS  = keyS + 131072;            // 131,072
    float* w2tK  = valS + 131072;            // 131,072
    float* w2tV  = w2tK + 131072;            // 131,072
    float* Uc    = w2tV + 131072;            // 12,288
    float* Vc    = Uc + 12288;               // 12,288

    constexpr int CLP_ENC = kC * PL_ENC;   // 768
    constexpr int CLP_DEC = kC * PL_DEC;   // 1280

    hipMemsetAsync(Ht, 0, (size_t)16384 * kH * sizeof(float), stream);

    // ---- weight preps ----
    k_prep_wt<<<(2*128*KP_ENC + 255)/256, 256, 0, stream>>>(enc_gW, WTg_e, L_ENC, PL_ENC, KP_ENC, 128);
    k_prep_wt<<<(2*64 *KP_ENC + 255)/256, 256, 0, stream>>>(enc_cW, WTc_e, L_ENC, PL_ENC, KP_ENC, 64);
    k_prep_wt<<<(2*128*KP_DEC + 255)/256, 256, 0, stream>>>(dec_gW, WTg_d, L_DEC, PL_DEC, KP_DEC, 128);
    k_prep_wt<<<(2*64 *KP_DEC + 255)/256, 256, 0, stream>>>(dec_cW, WTc_d, L_DEC, PL_DEC, KP_DEC, 64);
    k_prep_w2t<<<512, 256, 0, stream>>>(mfS_w2, w2tK, w2tV);

    // ---- phase 1: spatial graph ----
    k_uvproj_s<<<(kN*kBT*kH + 255)/256, 256, 0, stream>>>(X, WuS, WvS, Upr, Vpr);
    k_gemm_ntsk<<<dim3(8, 8, 4), 256, 0, stream>>>(Upr, Vpr, part, 512, 512, 1536, 384);
    k_redep<<<1024, 256, 0, stream>>>(part, 4, 262144, 512, Ms, 0, nullptr, nullptr);
    k_softmax_pm<<<kN, 256, 0, stream>>>(Ms, Ps, kN);
    k_nf<<<kN, 256, 0, stream>>>(As, Ps, nfS, kN);
    k_anpn<<<kN, 256, 0, stream>>>(As, Ps, nfS, AnS, PnS, kN);
    k_mlp1cat<<<1024, 256, 0, stream>>>(AnS, PnS, mfS_w1, mfS_b1, 0, 1, hidAP);
    k_gemm_ntsk<<<dim3(4, 8, 2), 256, 0, stream>>>(hidAP, w2tK, part, 512, 256, 512, 256);
    k_redep<<<512, 256, 0, stream>>>(part, 2, 131072, 256, keyS, 2, mfS_b2, mfS_b2 + 256);
    k_mlp1cat<<<1024, 256, 0, stream>>>(AnS, PnS, mfS_w1, mfS_b1, 2, 3, hidAP);
    k_gemm_ntsk<<<dim3(4, 8, 2), 256, 0, stream>>>(hidAP, w2tV, part, 512, 256, 512, 256);
    k_redep<<<512, 256, 0, stream>>>(part, 2, 131072, 256, valS, 2, mfS_b2 + 512, mfS_b2 + 768);
    k_gemm_ntsk<<<dim3(8, 8, 2), 256, 0, stream>>>(keyS, valS, part, 512, 512, 256, 128);
    k_redep<<<1024, 256, 0, stream>>>(part, 2, 262144, 512, Gs, 1, As, Ps);
    k_transp<<<dim3(16, 16), dim3(32, 8), 0, stream>>>(Gs, GstB);
    k_cheby_mfma<<<dim3(4, 4), 256, 0, stream>>>(GstB, GstB + 262144);

    // ---- phase 1: categorical graph ----
    k_uvproj_c<<<(kBT*kC*kH + 255)/256, 256, 0, stream>>>(X, WuC, WvC, Uc, Vc);
    k_mc<<<1, 64, 0, stream>>>(Uc, Vc, McB);
    k_softmax_pm<<<kC, 256, 0, stream>>>(McB, PcB, kC);
    k_nf<<<kC, 256, 0, stream>>>(Ac, PcB, nfC, kC);
    k_anpn<<<kC, 256, 0, stream>>>(Ac, PcB, nfC, AnC, PnC, kC);
    k_catmlp<<<dim3(2, 4), 256, 0, stream>>>(AnC, PnC, mfC_w1, mfC_b1, mfC_w2, mfC_b2, kvC);
    k_gcfuse<<<1, 64, 0, stream>>>(kvC, Ac, PcB, GcF);

    // ---- encoder ----
    for (int t = 0; t < kT; ++t) {
        k_build_enc<<<(16384*PL_ENC + 255)/256, 256, 0, stream>>>(X, t, Ht, featr, XHb);
        k_t1_mfma<CLP_ENC><<<dim3(CLP_ENC/128, 4, 8), 256, 0, stream>>>(GstB, XHb, Yb);
        k_gg_mfma<PL_ENC, KP_ENC, 4><<<dim3(2, 128), 256, 0, stream>>>(XHb, Yb, WTg_e, Gg, 256);
        k_gates_ep<PL_ENC, 1><<<2048, 256, 0, stream>>>(Gg, GcF, enc_gb, Ht, updb, XHb);
        k_t1_mfma<CLP_ENC><<<dim3(CLP_ENC/128, 4, 8), 256, 0, stream>>>(GstB, XHb, Yb);
        k_gg_mfma<PL_ENC, KP_ENC, 2><<<dim3(2, 128), 256, 0, stream>>>(XHb, Yb, WTc_e, Gg, 128);
        k_cand_ep<<<2048, 256, 0, stream>>>(Gg, GcF, enc_cb, updb, Ht);
    }

    // ---- decoder ----
    for (int hz = 0; hz < kHOR; ++hz) {
        k_build_dec<<<(16384*PL_DEC + 255)/256, 256, 0, stream>>>(Ht, featr, XHb);
        k_t1_mfma<CLP_DEC><<<dim3(CLP_DEC/128, 4, 8), 256, 0, stream>>>(GstB, XHb, Yb);
        k_gg_mfma<PL_DEC, KP_DEC, 4><<<dim3(2, 128), 256, 0, stream>>>(XHb, Yb, WTg_d, Gg, 256);
        k_gates_ep<PL_DEC, kH><<<2048, 256, 0, stream>>>(Gg, GcF, dec_gb, Ht, updb, XHb);
        k_t1_mfma<CLP_DEC><<<dim3(CLP_DEC/128, 4, 8), 256, 0, stream>>>(GstB, XHb, Yb);
        k_gg_mfma<PL_DEC, KP_DEC, 2><<<dim3(2, 128), 256, 0, stream>>>(XHb, Yb, WTc_d, Gg, 128);
        k_cand_ep<<<2048, 256, 0, stream>>>(Gg, GcF, dec_cb, updb, Ht);
        k_outmlp<<<(kB*kN*kC + 255)/256, 256, 0, stream>>>(Ht, out_w1, out_b1, out_w2, out_b2, out, hz);
    }
}